// Round 15
// baseline (720.532 us; speedup 1.0000x reference)
//
#include <hip/hip_runtime.h>
#include <stdint.h>

#define T_TOK 8192
#define DMODEL 1024
#define FDIM 4096
#define NEXP 8
#define NROWS 16384      // T_TOK * K
#define MAXT 80          // max 256-row tiles

// prep_kernel block ranges
#define GATE_BLKS 2048                  // T_TOK/4
#define CVT_BLKS  4096                  // T*D/8/256
#define TRW_BLKS  4096                  // 16384 wave-items (64kx64n tiles) / 4
#define PREP_BLKS (GATE_BLKS + CVT_BLKS + TRW_BLKS)

typedef __bf16 bf16x8 __attribute__((ext_vector_type(8)));
typedef float f32x4 __attribute__((ext_vector_type(4)));
#define AS1 __attribute__((address_space(1)))
#define AS3 __attribute__((address_space(3)))

__device__ __forceinline__ unsigned short f2bf(float f) {
  union { float f; unsigned u; } v; v.f = f;
  unsigned r = v.u + 0x7fffu + ((v.u >> 16) & 1u);
  return (unsigned short)(r >> 16);
}
__device__ __forceinline__ float bflo(unsigned u) {
  union { unsigned u; float f; } v; v.u = u << 16; return v.f;
}
__device__ __forceinline__ float bfhi(unsigned u) {
  union { unsigned u; float f; } v; v.u = u & 0xffff0000u; return v.f;
}

// ---- register micro-tile transpose: [Kdim][Ndim] f32 -> chunked [kt][n][64] bf16
// Wave owns 64k x 64n; lane owns 8k x 8n. THREE STRICT PHASES:
//  1) issue ALL 16 float4 loads into va/vb (64 VGPR) -- 16 loads in flight/lane
//  2) convert+pack to 32 packed-bf16 VGPRs (lane-local, compile-time indices)
//  3) 8x uint4 stores; each klane-group covers a full 128B line (no write amp)
// No LDS, no syncthreads. VGPR ~100 -> ~5 waves/SIMD.
__device__ __forceinline__ void wave_tr8(
    const float* __restrict__ in, unsigned short* __restrict__ out,
    int Kdim, int Ndim, int e, int kt, int nt64, int lane)
{
  size_t ebase = (size_t)e * Kdim * Ndim;
  const int nlane = lane & 7, klane = lane >> 3;
  const int k0 = kt * 64 + klane * 8;
  const int n0 = nt64 * 64 + nlane * 8;
  const float* src = in + ebase + (size_t)k0 * Ndim + n0;
  // phase 1: all 16 loads issued before any use
  float4 va[8], vb[8];
#pragma unroll
  for (int j = 0; j < 8; ++j) {
    va[j] = *(const float4*)(src + (size_t)j * Ndim);
    vb[j] = *(const float4*)(src + (size_t)j * Ndim + 4);
  }
  // phase 2: convert + pack (2 bf16 per VGPR)
  unsigned h2[8][4];
#pragma unroll
  for (int j = 0; j < 8; ++j) {
    h2[j][0] = (unsigned)f2bf(va[j].x) | ((unsigned)f2bf(va[j].y) << 16);
    h2[j][1] = (unsigned)f2bf(va[j].z) | ((unsigned)f2bf(va[j].w) << 16);
    h2[j][2] = (unsigned)f2bf(vb[j].x) | ((unsigned)f2bf(vb[j].y) << 16);
    h2[j][3] = (unsigned)f2bf(vb[j].z) | ((unsigned)f2bf(vb[j].w) << 16);
  }
  // phase 3: 8 contiguous 16B stores (klane-group = dense 128B line)
  unsigned short* dst = out + ebase + ((size_t)kt * Ndim + n0) * 64 + klane * 8;
#pragma unroll
  for (int i = 0; i < 8; ++i) {
    union { unsigned short h[8]; uint4 q; } pk;
#pragma unroll
    for (int j = 0; j < 8; ++j) {
      unsigned v = h2[j][i >> 1];
      pk.h[j] = (unsigned short)((i & 1) ? (v >> 16) : (v & 0xffffu));
    }
    *(uint4*)(dst + (size_t)i * 64) = pk.q;
  }
}

// ---------------- fused prep: gate || f32->bf16 cvt || both W transposes ------
__global__ __launch_bounds__(256) void prep_kernel(
    const float* __restrict__ gx, const float* __restrict__ Wg,
    const float* __restrict__ bg, int* __restrict__ sel,
    float* __restrict__ wts, int* __restrict__ counts,
    const float* __restrict__ inputs, unsigned short* __restrict__ Xb,
    const float* __restrict__ w1, unsigned short* __restrict__ W1T,
    const float* __restrict__ w2, unsigned short* __restrict__ W2T)
{
  int b = blockIdx.x;
  if (b < GATE_BLKS) {
    int t = b * 4 + (threadIdx.x >> 6);
    int lane = threadIdx.x & 63;
    const float* row = gx + (size_t)t * DMODEL;
    float acc[NEXP];
#pragma unroll
    for (int e = 0; e < NEXP; ++e) acc[e] = 0.f;
    for (int d = lane; d < DMODEL; d += 64) {
      float x = row[d];
      const float* wgr = Wg + (size_t)d * NEXP;
#pragma unroll
      for (int e = 0; e < NEXP; ++e) acc[e] += x * wgr[e];
    }
#pragma unroll
    for (int off = 32; off > 0; off >>= 1) {
#pragma unroll
      for (int e = 0; e < NEXP; ++e) acc[e] += __shfl_down(acc[e], off);
    }
    if (lane == 0) {
      float lg[NEXP];
#pragma unroll
      for (int e = 0; e < NEXP; ++e) lg[e] = acc[e] + bg[e];
      int i1 = 0; float v1 = lg[0];
#pragma unroll
      for (int e = 1; e < NEXP; ++e) if (lg[e] > v1) { v1 = lg[e]; i1 = e; }
      int i2 = -1; float v2 = -3.4e38f;
#pragma unroll
      for (int e = 0; e < NEXP; ++e) if (e != i1 && lg[e] > v2) { v2 = lg[e]; i2 = e; }
      float ez = __expf(v2 - v1);           // v2 <= v1
      float s = 1.f / (1.f + ez);
      sel[t*2] = i1; sel[t*2+1] = i2;
      wts[t*2] = s;  wts[t*2+1] = ez * s;
      atomicAdd(&counts[i1], 1);
      atomicAdd(&counts[i2], 1);
    }
  } else if (b < GATE_BLKS + CVT_BLKS) {
    int i = (b - GATE_BLKS) * 256 + threadIdx.x;
    const float4* in4 = (const float4*)inputs;
    float4 v0 = in4[(size_t)i*2], v1 = in4[(size_t)i*2 + 1];
    union { unsigned short u[8]; uint4 q; } r;
    r.u[0]=f2bf(v0.x); r.u[1]=f2bf(v0.y); r.u[2]=f2bf(v0.z); r.u[3]=f2bf(v0.w);
    r.u[4]=f2bf(v1.x); r.u[5]=f2bf(v1.y); r.u[6]=f2bf(v1.z); r.u[7]=f2bf(v1.w);
    ((uint4*)Xb)[i] = r.q;
  } else {
    // transpose wave-items: w1 first 8192, then w2 8192
    int gw = (b - GATE_BLKS - CVT_BLKS) * 4 + (threadIdx.x >> 6);
    int lane = threadIdx.x & 63;
    if (gw < 8192) {
      // w1 [E][K=1024][N=4096]: 1024 tiles/expert = kt(16) x nt(64)
      int e = gw >> 10, rem = gw & 1023;
      wave_tr8(w1, W1T, DMODEL, FDIM, e, rem >> 6, rem & 63, lane);
    } else {
      // w2 [E][K=4096][N=1024]: 1024 tiles/expert = kt(64) x nt(16)
      int g2 = gw - 8192;
      int e = g2 >> 10, rem = g2 & 1023;
      wave_tr8(w2, W2T, FDIM, DMODEL, e, rem >> 4, rem & 15, lane);
    }
  }
}

// ---------------- offsets + 256-row tile table (parallel, 1 block) ------------
__global__ __launch_bounds__(256) void scan_build_kernel(
    const int* __restrict__ counts, int* __restrict__ offsets,
    int* __restrict__ ntiles, int* __restrict__ t_e, int* __restrict__ t_r,
    int* __restrict__ t_rend)
{
  __shared__ int sc[8], soff[9], stile[9];
  int tid = threadIdx.x;
  if (tid < 8) sc[tid] = counts[tid];
  __syncthreads();
  if (tid == 0) {
    int off = 0, tl = 0;
#pragma unroll
    for (int e = 0; e < NEXP; ++e) {
      soff[e] = off; stile[e] = tl;
      off += sc[e];
      tl += (sc[e] + 255) >> 8;
    }
    soff[8] = off; stile[8] = tl;
  }
  __syncthreads();
  int ntot = stile[8];
  for (int idx = tid; idx < ntot; idx += 256) {
    int e = 0;
#pragma unroll
    for (int q = 0; q < NEXP; ++q) if (idx >= stile[q + 1]) e = q + 1;
    int r = (idx - stile[e]) * 256;
    t_e[idx] = e; t_r[idx] = soff[e] + r; t_rend[idx] = soff[e] + sc[e];
  }
  if (tid < 9) offsets[tid] = soff[tid];
  if (tid == 0) *ntiles = ntot;
}

// ---------------- scatter: wave-aggregated per-expert atomics -----------------
__global__ __launch_bounds__(256) void scatter_kernel(
    const int* __restrict__ sel, int* __restrict__ cursors,
    const int* __restrict__ offsets, int* __restrict__ token_list,
    int* __restrict__ slot_list)
{
  int t = blockIdx.x * 256 + threadIdx.x;
  int lane = threadIdx.x & 63;
  unsigned long long ltmask = (lane == 63) ? 0x7fffffffffffffffull
                                           : ((1ull << lane) - 1ull);
#pragma unroll
  for (int k = 0; k < 2; ++k) {
    int e = sel[t*2 + k];
#pragma unroll
    for (int ex = 0; ex < NEXP; ++ex) {
      unsigned long long m = __ballot(e == ex);
      if (m == 0ull) continue;
      if (e == ex) {
        int leader = __ffsll((unsigned long long)m) - 1;
        int cnt = __popcll(m);
        int base = 0;
        if (lane == leader) base = atomicAdd(&cursors[ex], cnt);
        base = __shfl(base, leader);
        int r = offsets[ex] + base + __popcll(m & ltmask);
        token_list[r] = t;
        slot_list[r] = t*2 + k;
      }
    }
  }
}

// ---------------- grouped GEMM 256x256, BK=64, 4-phase counted-vmcnt ----------
// Schedule unchanged from R9 (verified). B read from chunked [e][kt][n][64].
template<bool G1>
__global__ __launch_bounds__(512, 2) void gemm256_kernel(
    const unsigned short* __restrict__ A, const unsigned short* __restrict__ B,
    const float* __restrict__ b1, const int* __restrict__ token_list,
    const int* __restrict__ slot_list,
    const int* __restrict__ tile_e, const int* __restrict__ tile_r,
    const int* __restrict__ tile_rend, const int* __restrict__ ntiles,
    unsigned short* __restrict__ outp)
{
  constexpr int KDIM = G1 ? DMODEL : FDIM;   // K extent
  constexpr int NKT  = KDIM / 64;
  constexpr int NOUT = G1 ? FDIM : DMODEL;   // output row width
  constexpr int KTB  = NOUT * 64;            // B k-tile stride (elements)

  int bid = blockIdx.x;
  int nb, bt;
  if constexpr (G1) {                        // 16 nb-panels: pin 2 per XCD, bt-major
    int xcd = bid & 7, idx = bid >> 3;
    nb = xcd * 2 + (idx & 1);
    bt = idx >> 1;
  } else {                                   // 4 nb-panels, bt-major
    nb = bid & 3;
    bt = bid >> 2;
  }
  if (bt >= *ntiles) return;
  const int e = tile_e[bt], row0 = tile_r[bt], rend = tile_rend[bt];
  const int n0 = nb * 256;

  const int tid = threadIdx.x, lane = tid & 63, wave = tid >> 6;
  extern __shared__ __align__(16) char smem[];   // 131072 B

  const int lr8 = lane >> 3, g8 = lane & 7, ch = g8 ^ lr8;

  int mA[2], mB[2];
#pragma unroll
  for (int p = 0; p < 2; ++p)
    mA[p] = (wave < 4) ? (p*64 + wave*16) : (128 + p*64 + (wave-4)*16);
#pragma unroll
  for (int nh = 0; nh < 2; ++nh)
    mB[nh] = (wave >> 1)*64 + nh*32 + (wave & 1)*16;

  const unsigned short* eB = B + (size_t)e * KDIM * NOUT;
  unsigned aoffs[2][2], boffs[2][2];
#pragma unroll
  for (int p = 0; p < 2; ++p)
#pragma unroll
    for (int l = 0; l < 2; ++l) {
      int m = mA[p] + l*8 + lr8;
      int row = row0 + m; if (row > NROWS - 1) row = NROWS - 1;
      int arow = G1 ? token_list[row] : row;
      aoffs[p][l] = (unsigned)arow * KDIM + ch*8;
      int mb = mB[p] + l*8 + lr8;
      boffs[p][l] = (unsigned)((n0 + mb) * 64 + ch*8);
    }

  auto stage_half = [&](int p, int ktn, int bsel) {
    char* base = smem + bsel * 65536;
    if (p < 2) {
      const int kb = ktn * 64;
#pragma unroll
      for (int l = 0; l < 2; ++l)
        __builtin_amdgcn_global_load_lds(
            (const AS1 void*)(A + aoffs[p][l] + kb),
            (AS3 void*)(base + ((mA[p] + l*8) << 7)), 16, 0, 0);
    } else {
      const int nh = p - 2;
      const unsigned short* bk = eB + (size_t)ktn * KTB;
#pragma unroll
      for (int l = 0; l < 2; ++l)
        __builtin_amdgcn_global_load_lds(
            (const AS1 void*)(bk + boffs[nh][l]),
            (AS3 void*)(base + 32768 + ((mB[nh] + l*8) << 7)), 16, 0, 0);
    }
  };

  f32x4 acc[8][4] = {};
  bf16x8 aR[4][2];        // current A-half: 4 row-frags x 2 k-slices
  bf16x8 bR[2][2][2];     // both B-halves: [nh][jj][ks]
  const int wr = wave >> 2, wc = wave & 3;
  const int lm = lane & 15, lk = lane >> 4, l7 = lane & 7;
  const unsigned abase = (unsigned)(wr*128 + lm) * 128;
  const unsigned bbase = 32768u + (unsigned)(wc*64 + lm) * 128;
  const unsigned kx0 = (unsigned)((lk ^ l7) << 4);
  const unsigned kx1 = (unsigned)(((4 + lk) ^ l7) << 4);

  auto rdA = [&](const char* base, int mh) {
#pragma unroll
    for (int i = 0; i < 4; ++i) {
      const char* pA = base + abase + mh*8192 + i*2048;
      aR[i][0] = *(const bf16x8*)(pA + kx0);
      aR[i][1] = *(const bf16x8*)(pA + kx1);
    }
  };
  auto rdB = [&](const char* base, int nh) {
#pragma unroll
    for (int jj = 0; jj < 2; ++jj) {
      const char* pB = base + bbase + nh*4096 + jj*2048;
      bR[nh][jj][0] = *(const bf16x8*)(pB + kx0);
      bR[nh][jj][1] = *(const bf16x8*)(pB + kx1);
    }
  };
  auto mm = [&](int mh, int nh) {
    __builtin_amdgcn_s_setprio(1);
#pragma unroll
    for (int i = 0; i < 4; ++i)
#pragma unroll
      for (int jj = 0; jj < 2; ++jj) {
        acc[mh*4+i][nh*2+jj] = __builtin_amdgcn_mfma_f32_16x16x32_bf16(
            aR[i][0], bR[nh][jj][0], acc[mh*4+i][nh*2+jj], 0, 0, 0);
        acc[mh*4+i][nh*2+jj] = __builtin_amdgcn_mfma_f32_16x16x32_bf16(
            aR[i][1], bR[nh][jj][1], acc[mh*4+i][nh*2+jj], 0, 0, 0);
      }
    __builtin_amdgcn_s_setprio(0);
  };

  // prologue: stage tile 0 halves in consumption order A0,B0,B1,A1
  stage_half(0, 0, 0);
  stage_half(2, 0, 0);
  stage_half(3, 0, 0);
  stage_half(1, 0, 0);

  for (int kt = 0; kt < NKT; ++kt) {
    const int b = kt & 1;
    const int nxt = b ^ 1;
    const char* base = smem + b * 65536;
    const bool pre = (kt + 1 < NKT);
    // ---- P0: quad (0,0); needs A0,B0 ----
    if (pre) {
      stage_half(0, kt + 1, nxt);
      asm volatile("s_waitcnt vmcnt(6)" ::: "memory");
    } else {
      asm volatile("s_waitcnt vmcnt(4)" ::: "memory");
    }
    __builtin_amdgcn_s_barrier();
    __builtin_amdgcn_sched_barrier(0);
    rdA(base, 0); rdB(base, 0);
    asm volatile("s_waitcnt lgkmcnt(0)" ::: "memory");
    __builtin_amdgcn_sched_barrier(0);
    mm(0, 0);
    __builtin_amdgcn_s_barrier();
    // ---- P1: quad (0,1); needs B1 ----
    if (pre) {
      stage_half(2, kt + 1, nxt);
      asm volatile("s_waitcnt vmcnt(6)" ::: "memory");
    } else {
      asm volatile("s_waitcnt vmcnt(2)" ::: "memory");
    }
    __builtin_amdgcn_s_barrier();
    __builtin_amdgcn_sched_barrier(0);
    rdB(base, 1);
    asm volatile("s_waitcnt lgkmcnt(0)" ::: "memory");
    __builtin_amdgcn_sched_barrier(0);
    mm(0, 1);
    __builtin_amdgcn_s_barrier();
    // ---- P2: quad (1,1); needs A1 ----
    if (pre) {
      stage_half(3, kt + 1, nxt);
      asm volatile("s_waitcnt vmcnt(6)" ::: "memory");
    } else {
      asm volatile("s_waitcnt vmcnt(0)" ::: "memory");
    }
    __builtin_amdgcn_s_barrier();
    __builtin_amdgcn_sched_barrier(0);
    rdA(base, 1);
    asm volatile("s_waitcnt lgkmcnt(0)" ::: "memory");
    __builtin_amdgcn_sched_barrier(0);
    mm(1, 1);
    __builtin_amdgcn_s_barrier();
    // ---- P3: quad (1,0); no reads ----
    if (pre) stage_half(1, kt + 1, nxt);
    mm(1, 0);
    __builtin_amdgcn_s_barrier();
    __builtin_amdgcn_sched_barrier(0);
  }

  asm volatile("" ::: "memory");
  float bias[4] = {};
  if constexpr (G1) {
#pragma unroll
    for (int j = 0; j < 4; ++j) bias[j] = b1[(size_t)e * FDIM + n0 + wc*64 + j*16 + lm];
  }

  // epilogue: 8 chunks of 32 rows; [gelu] -> f32 LDS (stride 260) -> bf16 x8
  float* eps = (float*)smem;
#pragma unroll
  for (int c = 0; c < 8; ++c) {
    __syncthreads();
    if (wr == (c >> 2)) {
#pragma unroll
      for (int ii = 0; ii < 2; ++ii) {
        const int mi = (c & 3) * 2 + ii;
#pragma unroll
        for (int j = 0; j < 4; ++j) {
#pragma unroll
          for (int r = 0; r < 4; ++r) {
            float v = acc[mi][j][r];
            if constexpr (G1) {
              v += bias[j];
              float z2 = 1.5957691216f * (v + 0.044715f * v * v * v);
              v = v / (1.f + __expf(-z2));
            }
            eps[(ii*16 + lk*4 + r) * 260 + wc*64 + j*16 + lm] = v;
          }
        }
      }
    }
    __syncthreads();
#pragma unroll
    for (int u = 0; u < 2; ++u) {
      int item = u * 512 + tid;               // 1024 items: 32 rows x 32 octs
      int lrow = item >> 5, c8 = (item & 31) * 8;
      int gr = row0 + c * 32 + lrow;
      if (gr < rend) {
        float4 v0 = *(const float4*)&eps[lrow * 260 + c8];
        float4 v1 = *(const float4*)&eps[lrow * 260 + c8 + 4];
        union { unsigned short u[8]; uint4 q; } pk;
        pk.u[0]=f2bf(v0.x); pk.u[1]=f2bf(v0.y); pk.u[2]=f2bf(v0.z); pk.u[3]=f2bf(v0.w);
        pk.u[4]=f2bf(v1.x); pk.u[5]=f2bf(v1.y); pk.u[6]=f2bf(v1.z); pk.u[7]=f2bf(v1.w);
        size_t orow;
        if constexpr (G1) orow = (size_t)gr * FDIM;
        else              orow = (size_t)slot_list[gr] * DMODEL;
        *(uint4*)(outp + orow + n0 + c8) = pk.q;
      }
    }
  }
}

// ---------------- combine: out = sum_k w_k*(y_k + b2[e_k]) --------------------
__global__ __launch_bounds__(256) void combine_kernel(
    const unsigned short* __restrict__ ys, const float* __restrict__ wts,
    const int* __restrict__ sel, const float* __restrict__ b2,
    float* __restrict__ out)
{
  int i = blockIdx.x * 256 + threadIdx.x;   // over T*D/8
  int t = i >> 7, d8 = i & 127;
  float w0 = wts[t*2], w1 = wts[t*2 + 1];
  int e0 = sel[t*2], e1 = sel[t*2 + 1];
  const uint4* ys4 = (const uint4*)ys;
  uint4 ya = ys4[(size_t)(t*2) * 128 + d8];
  uint4 yb = ys4[(size_t)(t*2 + 1) * 128 + d8];
  const float4* b24 = (const float4*)b2;
  float4 c0a = b24[e0*256 + d8*2], c0b = b24[e0*256 + d8*2 + 1];
  float4 c1a = b24[e1*256 + d8*2], c1b = b24[e1*256 + d8*2 + 1];
  float4 o0, o1;
  o0.x = w0*(bflo(ya.x)+c0a.x) + w1*(bflo(yb.x)+c1a.x);
  o0.y = w0*(bfhi(ya.x)+c0a.y) + w1*(bfhi(yb.x)+c1a.y);
  o0.z = w0*(bflo(ya.y)+c0a.z) + w1*(bflo(yb.y)+c1a.z);
  o0.w = w0*(bfhi(ya.y)+c0a.w) + w1*(bfhi(yb.y)+c1a.w);
  o1.x = w0*(bflo(ya.z)+c0b.x) + w1*(bflo(yb.z)+c1b.x);
  o1.y = w0*(bfhi(ya.z)+c0b.y) + w1*(bfhi(yb.z)+c1b.y);
  o1.z = w0*(bflo(ya.w)+c0b.z) + w1*(bflo(yb.w)+c1b.z);
  o1.w = w0*(bfhi(ya.w)+c0b.w) + w1*(bfhi(yb.w)+c1b.w);
  float4* out4 = (float4*)out;
  out4[(size_t)t * 256 + d8*2]     = o0;
  out4[(size_t)t * 256 + d8*2 + 1] = o1;
}

// ---------------- host ---------------------------------------------------------
extern "C" void kernel_launch(void* const* d_in, const int* in_sizes, int n_in,
                              void* d_out, int out_size, void* d_ws, size_t ws_size,
                              hipStream_t stream)
{
  const float* gate_inputs = (const float*)d_in[0];
  const float* inputs      = (const float*)d_in[1];
  const float* Wg          = (const float*)d_in[2];
  const float* bg          = (const float*)d_in[3];
  const float* w1          = (const float*)d_in[4];
  const float* b1          = (const float*)d_in[5];
  const float* w2          = (const float*)d_in[6];
  const float* b2          = (const float*)d_in[7];
  float* out = (float*)d_out;

  char* ws = (char*)d_ws;
  size_t o = 0;
  auto carve = [&](size_t bytes) { void* p = ws + o; o += (bytes + 255) & ~(size_t)255; return p; };
  unsigned short* Xb  = (unsigned short*)carve((size_t)T_TOK * DMODEL * 2);
  unsigned short* W1T = (unsigned short*)carve((size_t)NEXP * FDIM * DMODEL * 2);
  unsigned short* W2T = (unsigned short*)carve((size_t)NEXP * DMODEL * FDIM * 2);
  unsigned short* H   = (unsigned short*)carve((size_t)NROWS * FDIM * 2);
  unsigned short* ys  = (unsigned short*)carve((size_t)NROWS * DMODEL * 2);
  int*   sel          = (int*)carve((size_t)NROWS * 4);
  float* wts          = (float*)carve((size_t)NROWS * 4);
  int*   token_list   = (int*)carve((size_t)(NROWS + 256) * 4);
  int*   slot_list    = (int*)carve((size_t)(NROWS + 256) * 4);
  int*   ctrl         = (int*)carve(4096);
  int* counts  = ctrl;            // 8
  int* cursors = ctrl + 8;        // 8
  int* offsets = ctrl + 16;       // 9
  int* ntiles  = ctrl + 28;       // 1
  int* t_e     = ctrl + 32;
  int* t_r     = ctrl + 32 + MAXT;
  int* t_rend  = ctrl + 32 + 2 * MAXT;

  hipMemsetAsync(counts, 0, 64, stream);  // counts + cursors

  prep_kernel<<<PREP_BLKS, 256, 0, stream>>>(
      gate_inputs, Wg, bg, sel, wts, counts,
      inputs, Xb, w1, W1T, w2, W2T);
  scan_build_kernel<<<1, 256, 0, stream>>>(counts, offsets, ntiles, t_e, t_r, t_rend);
  scatter_kernel<<<T_TOK / 256, 256, 0, stream>>>(sel, cursors, offsets, token_list, slot_list);

  hipFuncSetAttribute((const void*)gemm256_kernel<true>,
                      hipFuncAttributeMaxDynamicSharedMemorySize, 131072);
  hipFuncSetAttribute((const void*)gemm256_kernel<false>,
                      hipFuncAttributeMaxDynamicSharedMemorySize, 131072);
  // gemm1: H = gelu(X@W1+b1). grid = 8 xcd * (2 nb-sub * 80 bt)
  gemm256_kernel<true><<<8 * 2 * MAXT, 512, 131072, stream>>>(
      Xb, W1T, b1, token_list, nullptr, t_e, t_r, t_rend, ntiles, H);
  // gemm2: ys = H@W2 scatter. grid = 4 nb * 80 bt
  gemm256_kernel<false><<<4 * MAXT, 512, 131072, stream>>>(
      H, W2T, nullptr, nullptr, slot_list, t_e, t_r, t_rend, ntiles, ys);
  combine_kernel<<<(T_TOK * DMODEL / 8) / 256, 256, 0, stream>>>(ys, wts, sel, b2, out);
}

// Round 16
// 708.110 us; speedup vs baseline: 1.0175x; 1.0175x over previous
//
#include <hip/hip_runtime.h>
#include <stdint.h>

#define T_TOK 8192
#define DMODEL 1024
#define FDIM 4096
#define NEXP 8
#define NROWS 16384      // T_TOK * K
#define MAXT 80          // max 256-row tiles

// prep_kernel block ranges
#define GATE_BLKS 2048                  // T_TOK/4
#define CVT_BLKS  4096                  // T*D/8/256
#define TRW_BLKS  4096                  // 16384 wave-items (64kx64n tiles) / 4
#define PREP_BLKS (GATE_BLKS + CVT_BLKS + TRW_BLKS)

typedef __bf16 bf16x8 __attribute__((ext_vector_type(8)));
typedef float f32x4 __attribute__((ext_vector_type(4)));
#define AS1 __attribute__((address_space(1)))
#define AS3 __attribute__((address_space(3)))

__device__ __forceinline__ unsigned short f2bf(float f) {
  union { float f; unsigned u; } v; v.f = f;
  unsigned r = v.u + 0x7fffu + ((v.u >> 16) & 1u);
  return (unsigned short)(r >> 16);
}
__device__ __forceinline__ float bflo(unsigned u) {
  union { unsigned u; float f; } v; v.u = u << 16; return v.f;
}
__device__ __forceinline__ float bfhi(unsigned u) {
  union { unsigned u; float f; } v; v.u = u & 0xffff0000u; return v.f;
}

// ---- register micro-tile transpose: [Kdim][Ndim] f32 -> chunked [kt][n][64] bf16
// Wave owns 64k x 64n; lane owns 8k x 8n. THREE PHASES, FENCED with
// sched_barrier(0) so the scheduler CANNOT sink loads to their uses (R15
// post-mortem: without the fence, compiler reserialized to 36 VGPR and kept
// only ~2 loads in flight). With the fence: 16 loads in flight/lane (256B),
// one s_waitcnt services all. VGPR ~100 -> 4 waves/SIMD, still ample.
__device__ __forceinline__ void wave_tr8(
    const float* __restrict__ in, unsigned short* __restrict__ out,
    int Kdim, int Ndim, int e, int kt, int nt64, int lane)
{
  size_t ebase = (size_t)e * Kdim * Ndim;
  const int nlane = lane & 7, klane = lane >> 3;
  const int k0 = kt * 64 + klane * 8;
  const int n0 = nt64 * 64 + nlane * 8;
  const float* src = in + ebase + (size_t)k0 * Ndim + n0;
  // phase 1: all 16 loads issued back-to-back
  float4 va[8], vb[8];
#pragma unroll
  for (int j = 0; j < 8; ++j) {
    va[j] = *(const float4*)(src + (size_t)j * Ndim);
    vb[j] = *(const float4*)(src + (size_t)j * Ndim + 4);
  }
  __builtin_amdgcn_sched_barrier(0);   // loads may NOT sink below this point
  // phase 2: convert + pack (2 bf16 per VGPR)
  unsigned h2[8][4];
#pragma unroll
  for (int j = 0; j < 8; ++j) {
    h2[j][0] = (unsigned)f2bf(va[j].x) | ((unsigned)f2bf(va[j].y) << 16);
    h2[j][1] = (unsigned)f2bf(va[j].z) | ((unsigned)f2bf(va[j].w) << 16);
    h2[j][2] = (unsigned)f2bf(vb[j].x) | ((unsigned)f2bf(vb[j].y) << 16);
    h2[j][3] = (unsigned)f2bf(vb[j].z) | ((unsigned)f2bf(vb[j].w) << 16);
  }
  __builtin_amdgcn_sched_barrier(0);
  // phase 3: 8 contiguous 16B stores (klane-group = dense 128B line)
  unsigned short* dst = out + ebase + ((size_t)kt * Ndim + n0) * 64 + klane * 8;
#pragma unroll
  for (int i = 0; i < 8; ++i) {
    union { unsigned short h[8]; uint4 q; } pk;
#pragma unroll
    for (int j = 0; j < 8; ++j) {
      unsigned v = h2[j][i >> 1];
      pk.h[j] = (unsigned short)((i & 1) ? (v >> 16) : (v & 0xffffu));
    }
    *(uint4*)(dst + (size_t)i * 64) = pk.q;
  }
}

// ---------------- fused prep: gate || f32->bf16 cvt || both W transposes ------
__global__ __launch_bounds__(256) void prep_kernel(
    const float* __restrict__ gx, const float* __restrict__ Wg,
    const float* __restrict__ bg, int* __restrict__ sel,
    float* __restrict__ wts, int* __restrict__ counts,
    const float* __restrict__ inputs, unsigned short* __restrict__ Xb,
    const float* __restrict__ w1, unsigned short* __restrict__ W1T,
    const float* __restrict__ w2, unsigned short* __restrict__ W2T)
{
  int b = blockIdx.x;
  if (b < GATE_BLKS) {
    int t = b * 4 + (threadIdx.x >> 6);
    int lane = threadIdx.x & 63;
    const float* row = gx + (size_t)t * DMODEL;
    float acc[NEXP];
#pragma unroll
    for (int e = 0; e < NEXP; ++e) acc[e] = 0.f;
    for (int d = lane; d < DMODEL; d += 64) {
      float x = row[d];
      const float* wgr = Wg + (size_t)d * NEXP;
#pragma unroll
      for (int e = 0; e < NEXP; ++e) acc[e] += x * wgr[e];
    }
#pragma unroll
    for (int off = 32; off > 0; off >>= 1) {
#pragma unroll
      for (int e = 0; e < NEXP; ++e) acc[e] += __shfl_down(acc[e], off);
    }
    if (lane == 0) {
      float lg[NEXP];
#pragma unroll
      for (int e = 0; e < NEXP; ++e) lg[e] = acc[e] + bg[e];
      int i1 = 0; float v1 = lg[0];
#pragma unroll
      for (int e = 1; e < NEXP; ++e) if (lg[e] > v1) { v1 = lg[e]; i1 = e; }
      int i2 = -1; float v2 = -3.4e38f;
#pragma unroll
      for (int e = 0; e < NEXP; ++e) if (e != i1 && lg[e] > v2) { v2 = lg[e]; i2 = e; }
      float ez = __expf(v2 - v1);           // v2 <= v1
      float s = 1.f / (1.f + ez);
      sel[t*2] = i1; sel[t*2+1] = i2;
      wts[t*2] = s;  wts[t*2+1] = ez * s;
      atomicAdd(&counts[i1], 1);
      atomicAdd(&counts[i2], 1);
    }
  } else if (b < GATE_BLKS + CVT_BLKS) {
    int i = (b - GATE_BLKS) * 256 + threadIdx.x;
    const float4* in4 = (const float4*)inputs;
    float4 v0 = in4[(size_t)i*2], v1 = in4[(size_t)i*2 + 1];
    union { unsigned short u[8]; uint4 q; } r;
    r.u[0]=f2bf(v0.x); r.u[1]=f2bf(v0.y); r.u[2]=f2bf(v0.z); r.u[3]=f2bf(v0.w);
    r.u[4]=f2bf(v1.x); r.u[5]=f2bf(v1.y); r.u[6]=f2bf(v1.z); r.u[7]=f2bf(v1.w);
    ((uint4*)Xb)[i] = r.q;
  } else {
    // transpose wave-items: w1 first 8192, then w2 8192
    int gw = (b - GATE_BLKS - CVT_BLKS) * 4 + (threadIdx.x >> 6);
    int lane = threadIdx.x & 63;
    if (gw < 8192) {
      // w1 [E][K=1024][N=4096]: 1024 tiles/expert = kt(16) x nt(64)
      int e = gw >> 10, rem = gw & 1023;
      wave_tr8(w1, W1T, DMODEL, FDIM, e, rem >> 6, rem & 63, lane);
    } else {
      // w2 [E][K=4096][N=1024]: 1024 tiles/expert = kt(64) x nt(16)
      int g2 = gw - 8192;
      int e = g2 >> 10, rem = g2 & 1023;
      wave_tr8(w2, W2T, FDIM, DMODEL, e, rem >> 4, rem & 15, lane);
    }
  }
}

// ---------------- offsets + 256-row tile table (parallel, 1 block) ------------
__global__ __launch_bounds__(256) void scan_build_kernel(
    const int* __restrict__ counts, int* __restrict__ offsets,
    int* __restrict__ ntiles, int* __restrict__ t_e, int* __restrict__ t_r,
    int* __restrict__ t_rend)
{
  __shared__ int sc[8], soff[9], stile[9];
  int tid = threadIdx.x;
  if (tid < 8) sc[tid] = counts[tid];
  __syncthreads();
  if (tid == 0) {
    int off = 0, tl = 0;
#pragma unroll
    for (int e = 0; e < NEXP; ++e) {
      soff[e] = off; stile[e] = tl;
      off += sc[e];
      tl += (sc[e] + 255) >> 8;
    }
    soff[8] = off; stile[8] = tl;
  }
  __syncthreads();
  int ntot = stile[8];
  for (int idx = tid; idx < ntot; idx += 256) {
    int e = 0;
#pragma unroll
    for (int q = 0; q < NEXP; ++q) if (idx >= stile[q + 1]) e = q + 1;
    int r = (idx - stile[e]) * 256;
    t_e[idx] = e; t_r[idx] = soff[e] + r; t_rend[idx] = soff[e] + sc[e];
  }
  if (tid < 9) offsets[tid] = soff[tid];
  if (tid == 0) *ntiles = ntot;
}

// ---------------- scatter: wave-aggregated per-expert atomics -----------------
__global__ __launch_bounds__(256) void scatter_kernel(
    const int* __restrict__ sel, int* __restrict__ cursors,
    const int* __restrict__ offsets, int* __restrict__ token_list,
    int* __restrict__ slot_list)
{
  int t = blockIdx.x * 256 + threadIdx.x;
  int lane = threadIdx.x & 63;
  unsigned long long ltmask = (lane == 63) ? 0x7fffffffffffffffull
                                           : ((1ull << lane) - 1ull);
#pragma unroll
  for (int k = 0; k < 2; ++k) {
    int e = sel[t*2 + k];
#pragma unroll
    for (int ex = 0; ex < NEXP; ++ex) {
      unsigned long long m = __ballot(e == ex);
      if (m == 0ull) continue;
      if (e == ex) {
        int leader = __ffsll((unsigned long long)m) - 1;
        int cnt = __popcll(m);
        int base = 0;
        if (lane == leader) base = atomicAdd(&cursors[ex], cnt);
        base = __shfl(base, leader);
        int r = offsets[ex] + base + __popcll(m & ltmask);
        token_list[r] = t;
        slot_list[r] = t*2 + k;
      }
    }
  }
}

// ---------------- grouped GEMM 256x256, BK=64, 4-phase counted-vmcnt ----------
// Schedule unchanged from R9 (verified). B read from chunked [e][kt][n][64].
template<bool G1>
__global__ __launch_bounds__(512, 2) void gemm256_kernel(
    const unsigned short* __restrict__ A, const unsigned short* __restrict__ B,
    const float* __restrict__ b1, const int* __restrict__ token_list,
    const int* __restrict__ slot_list,
    const int* __restrict__ tile_e, const int* __restrict__ tile_r,
    const int* __restrict__ tile_rend, const int* __restrict__ ntiles,
    unsigned short* __restrict__ outp)
{
  constexpr int KDIM = G1 ? DMODEL : FDIM;   // K extent
  constexpr int NKT  = KDIM / 64;
  constexpr int NOUT = G1 ? FDIM : DMODEL;   // output row width
  constexpr int KTB  = NOUT * 64;            // B k-tile stride (elements)

  int bid = blockIdx.x;
  int nb, bt;
  if constexpr (G1) {                        // 16 nb-panels: pin 2 per XCD, bt-major
    int xcd = bid & 7, idx = bid >> 3;
    nb = xcd * 2 + (idx & 1);
    bt = idx >> 1;
  } else {                                   // 4 nb-panels, bt-major
    nb = bid & 3;
    bt = bid >> 2;
  }
  if (bt >= *ntiles) return;
  const int e = tile_e[bt], row0 = tile_r[bt], rend = tile_rend[bt];
  const int n0 = nb * 256;

  const int tid = threadIdx.x, lane = tid & 63, wave = tid >> 6;
  extern __shared__ __align__(16) char smem[];   // 131072 B

  const int lr8 = lane >> 3, g8 = lane & 7, ch = g8 ^ lr8;

  int mA[2], mB[2];
#pragma unroll
  for (int p = 0; p < 2; ++p)
    mA[p] = (wave < 4) ? (p*64 + wave*16) : (128 + p*64 + (wave-4)*16);
#pragma unroll
  for (int nh = 0; nh < 2; ++nh)
    mB[nh] = (wave >> 1)*64 + nh*32 + (wave & 1)*16;

  const unsigned short* eB = B + (size_t)e * KDIM * NOUT;
  unsigned aoffs[2][2], boffs[2][2];
#pragma unroll
  for (int p = 0; p < 2; ++p)
#pragma unroll
    for (int l = 0; l < 2; ++l) {
      int m = mA[p] + l*8 + lr8;
      int row = row0 + m; if (row > NROWS - 1) row = NROWS - 1;
      int arow = G1 ? token_list[row] : row;
      aoffs[p][l] = (unsigned)arow * KDIM + ch*8;
      int mb = mB[p] + l*8 + lr8;
      boffs[p][l] = (unsigned)((n0 + mb) * 64 + ch*8);
    }

  auto stage_half = [&](int p, int ktn, int bsel) {
    char* base = smem + bsel * 65536;
    if (p < 2) {
      const int kb = ktn * 64;
#pragma unroll
      for (int l = 0; l < 2; ++l)
        __builtin_amdgcn_global_load_lds(
            (const AS1 void*)(A + aoffs[p][l] + kb),
            (AS3 void*)(base + ((mA[p] + l*8) << 7)), 16, 0, 0);
    } else {
      const int nh = p - 2;
      const unsigned short* bk = eB + (size_t)ktn * KTB;
#pragma unroll
      for (int l = 0; l < 2; ++l)
        __builtin_amdgcn_global_load_lds(
            (const AS1 void*)(bk + boffs[nh][l]),
            (AS3 void*)(base + 32768 + ((mB[nh] + l*8) << 7)), 16, 0, 0);
    }
  };

  f32x4 acc[8][4] = {};
  bf16x8 aR[4][2];        // current A-half: 4 row-frags x 2 k-slices
  bf16x8 bR[2][2][2];     // both B-halves: [nh][jj][ks]
  const int wr = wave >> 2, wc = wave & 3;
  const int lm = lane & 15, lk = lane >> 4, l7 = lane & 7;
  const unsigned abase = (unsigned)(wr*128 + lm) * 128;
  const unsigned bbase = 32768u + (unsigned)(wc*64 + lm) * 128;
  const unsigned kx0 = (unsigned)((lk ^ l7) << 4);
  const unsigned kx1 = (unsigned)(((4 + lk) ^ l7) << 4);

  auto rdA = [&](const char* base, int mh) {
#pragma unroll
    for (int i = 0; i < 4; ++i) {
      const char* pA = base + abase + mh*8192 + i*2048;
      aR[i][0] = *(const bf16x8*)(pA + kx0);
      aR[i][1] = *(const bf16x8*)(pA + kx1);
    }
  };
  auto rdB = [&](const char* base, int nh) {
#pragma unroll
    for (int jj = 0; jj < 2; ++jj) {
      const char* pB = base + bbase + nh*4096 + jj*2048;
      bR[nh][jj][0] = *(const bf16x8*)(pB + kx0);
      bR[nh][jj][1] = *(const bf16x8*)(pB + kx1);
    }
  };
  auto mm = [&](int mh, int nh) {
    __builtin_amdgcn_s_setprio(1);
#pragma unroll
    for (int i = 0; i < 4; ++i)
#pragma unroll
      for (int jj = 0; jj < 2; ++jj) {
        acc[mh*4+i][nh*2+jj] = __builtin_amdgcn_mfma_f32_16x16x32_bf16(
            aR[i][0], bR[nh][jj][0], acc[mh*4+i][nh*2+jj], 0, 0, 0);
        acc[mh*4+i][nh*2+jj] = __builtin_amdgcn_mfma_f32_16x16x32_bf16(
            aR[i][1], bR[nh][jj][1], acc[mh*4+i][nh*2+jj], 0, 0, 0);
      }
    __builtin_amdgcn_s_setprio(0);
  };

  // prologue: stage tile 0 halves in consumption order A0,B0,B1,A1
  stage_half(0, 0, 0);
  stage_half(2, 0, 0);
  stage_half(3, 0, 0);
  stage_half(1, 0, 0);

  for (int kt = 0; kt < NKT; ++kt) {
    const int b = kt & 1;
    const int nxt = b ^ 1;
    const char* base = smem + b * 65536;
    const bool pre = (kt + 1 < NKT);
    // ---- P0: quad (0,0); needs A0,B0 ----
    if (pre) {
      stage_half(0, kt + 1, nxt);
      asm volatile("s_waitcnt vmcnt(6)" ::: "memory");
    } else {
      asm volatile("s_waitcnt vmcnt(4)" ::: "memory");
    }
    __builtin_amdgcn_s_barrier();
    __builtin_amdgcn_sched_barrier(0);
    rdA(base, 0); rdB(base, 0);
    asm volatile("s_waitcnt lgkmcnt(0)" ::: "memory");
    __builtin_amdgcn_sched_barrier(0);
    mm(0, 0);
    __builtin_amdgcn_s_barrier();
    // ---- P1: quad (0,1); needs B1 ----
    if (pre) {
      stage_half(2, kt + 1, nxt);
      asm volatile("s_waitcnt vmcnt(6)" ::: "memory");
    } else {
      asm volatile("s_waitcnt vmcnt(2)" ::: "memory");
    }
    __builtin_amdgcn_s_barrier();
    __builtin_amdgcn_sched_barrier(0);
    rdB(base, 1);
    asm volatile("s_waitcnt lgkmcnt(0)" ::: "memory");
    __builtin_amdgcn_sched_barrier(0);
    mm(0, 1);
    __builtin_amdgcn_s_barrier();
    // ---- P2: quad (1,1); needs A1 ----
    if (pre) {
      stage_half(3, kt + 1, nxt);
      asm volatile("s_waitcnt vmcnt(6)" ::: "memory");
    } else {
      asm volatile("s_waitcnt vmcnt(0)" ::: "memory");
    }
    __builtin_amdgcn_s_barrier();
    __builtin_amdgcn_sched_barrier(0);
    rdA(base, 1);
    asm volatile("s_waitcnt lgkmcnt(0)" ::: "memory");
    __builtin_amdgcn_sched_barrier(0);
    mm(1, 1);
    __builtin_amdgcn_s_barrier();
    // ---- P3: quad (1,0); no reads ----
    if (pre) stage_half(1, kt + 1, nxt);
    mm(1, 0);
    __builtin_amdgcn_s_barrier();
    __builtin_amdgcn_sched_barrier(0);
  }

  asm volatile("" ::: "memory");
  float bias[4] = {};
  if constexpr (G1) {
#pragma unroll
    for (int j = 0; j < 4; ++j) bias[j] = b1[(size_t)e * FDIM + n0 + wc*64 + j*16 + lm];
  }

  // epilogue: 8 chunks of 32 rows; [gelu] -> f32 LDS (stride 260) -> bf16 x8
  float* eps = (float*)smem;
#pragma unroll
  for (int c = 0; c < 8; ++c) {
    __syncthreads();
    if (wr == (c >> 2)) {
#pragma unroll
      for (int ii = 0; ii < 2; ++ii) {
        const int mi = (c & 3) * 2 + ii;
#pragma unroll
        for (int j = 0; j < 4; ++j) {
#pragma unroll
          for (int r = 0; r < 4; ++r) {
            float v = acc[mi][j][r];
            if constexpr (G1) {
              v += bias[j];
              float z2 = 1.5957691216f * (v + 0.044715f * v * v * v);
              v = v / (1.f + __expf(-z2));
            }
            eps[(ii*16 + lk*4 + r) * 260 + wc*64 + j*16 + lm] = v;
          }
        }
      }
    }
    __syncthreads();
#pragma unroll
    for (int u = 0; u < 2; ++u) {
      int item = u * 512 + tid;               // 1024 items: 32 rows x 32 octs
      int lrow = item >> 5, c8 = (item & 31) * 8;
      int gr = row0 + c * 32 + lrow;
      if (gr < rend) {
        float4 v0 = *(const float4*)&eps[lrow * 260 + c8];
        float4 v1 = *(const float4*)&eps[lrow * 260 + c8 + 4];
        union { unsigned short u[8]; uint4 q; } pk;
        pk.u[0]=f2bf(v0.x); pk.u[1]=f2bf(v0.y); pk.u[2]=f2bf(v0.z); pk.u[3]=f2bf(v0.w);
        pk.u[4]=f2bf(v1.x); pk.u[5]=f2bf(v1.y); pk.u[6]=f2bf(v1.z); pk.u[7]=f2bf(v1.w);
        size_t orow;
        if constexpr (G1) orow = (size_t)gr * FDIM;
        else              orow = (size_t)slot_list[gr] * DMODEL;
        *(uint4*)(outp + orow + n0 + c8) = pk.q;
      }
    }
  }
}

// ---------------- combine: out = sum_k w_k*(y_k + b2[e_k]) --------------------
__global__ __launch_bounds__(256) void combine_kernel(
    const unsigned short* __restrict__ ys, const float* __restrict__ wts,
    const int* __restrict__ sel, const float* __restrict__ b2,
    float* __restrict__ out)
{
  int i = blockIdx.x * 256 + threadIdx.x;   // over T*D/8
  int t = i >> 7, d8 = i & 127;
  float w0 = wts[t*2], w1 = wts[t*2 + 1];
  int e0 = sel[t*2], e1 = sel[t*2 + 1];
  const uint4* ys4 = (const uint4*)ys;
  uint4 ya = ys4[(size_t)(t*2) * 128 + d8];
  uint4 yb = ys4[(size_t)(t*2 + 1) * 128 + d8];
  const float4* b24 = (const float4*)b2;
  float4 c0a = b24[e0*256 + d8*2], c0b = b24[e0*256 + d8*2 + 1];
  float4 c1a = b24[e1*256 + d8*2], c1b = b24[e1*256 + d8*2 + 1];
  float4 o0, o1;
  o0.x = w0*(bflo(ya.x)+c0a.x) + w1*(bflo(yb.x)+c1a.x);
  o0.y = w0*(bfhi(ya.x)+c0a.y) + w1*(bfhi(yb.x)+c1a.y);
  o0.z = w0*(bflo(ya.y)+c0a.z) + w1*(bflo(yb.y)+c1a.z);
  o0.w = w0*(bfhi(ya.y)+c0a.w) + w1*(bfhi(yb.y)+c1a.w);
  o1.x = w0*(bflo(ya.z)+c0b.x) + w1*(bflo(yb.z)+c1b.x);
  o1.y = w0*(bfhi(ya.z)+c0b.y) + w1*(bfhi(yb.z)+c1b.y);
  o1.z = w0*(bflo(ya.w)+c0b.z) + w1*(bflo(yb.w)+c1b.z);
  o1.w = w0*(bfhi(ya.w)+c0b.w) + w1*(bfhi(yb.w)+c1b.w);
  float4* out4 = (float4*)out;
  out4[(size_t)t * 256 + d8*2]     = o0;
  out4[(size_t)t * 256 + d8*2 + 1] = o1;
}

// ---------------- host ---------------------------------------------------------
extern "C" void kernel_launch(void* const* d_in, const int* in_sizes, int n_in,
                              void* d_out, int out_size, void* d_ws, size_t ws_size,
                              hipStream_t stream)
{
  const float* gate_inputs = (const float*)d_in[0];
  const float* inputs      = (const float*)d_in[1];
  const float* Wg          = (const float*)d_in[2];
  const float* bg          = (const float*)d_in[3];
  const float* w1          = (const float*)d_in[4];
  const float* b1          = (const float*)d_in[5];
  const float* w2          = (const float*)d_in[6];
  const float* b2          = (const float*)d_in[7];
  float* out = (float*)d_out;

  char* ws = (char*)d_ws;
  size_t o = 0;
  auto carve = [&](size_t bytes) { void* p = ws + o; o += (bytes + 255) & ~(size_t)255; return p; };
  unsigned short* Xb  = (unsigned short*)carve((size_t)T_TOK * DMODEL * 2);
  unsigned short* W1T = (unsigned short*)carve((size_t)NEXP * FDIM * DMODEL * 2);
  unsigned short* W2T = (unsigned short*)carve((size_t)NEXP * DMODEL * FDIM * 2);
  unsigned short* H   = (unsigned short*)carve((size_t)NROWS * FDIM * 2);
  unsigned short* ys  = (unsigned short*)carve((size_t)NROWS * DMODEL * 2);
  int*   sel          = (int*)carve((size_t)NROWS * 4);
  float* wts          = (float*)carve((size_t)NROWS * 4);
  int*   token_list   = (int*)carve((size_t)(NROWS + 256) * 4);
  int*   slot_list    = (int*)carve((size_t)(NROWS + 256) * 4);
  int*   ctrl         = (int*)carve(4096);
  int* counts  = ctrl;            // 8
  int* cursors = ctrl + 8;        // 8
  int* offsets = ctrl + 16;       // 9
  int* ntiles  = ctrl + 28;       // 1
  int* t_e     = ctrl + 32;
  int* t_r     = ctrl + 32 + MAXT;
  int* t_rend  = ctrl + 32 + 2 * MAXT;

  hipMemsetAsync(counts, 0, 64, stream);  // counts + cursors

  prep_kernel<<<PREP_BLKS, 256, 0, stream>>>(
      gate_inputs, Wg, bg, sel, wts, counts,
      inputs, Xb, w1, W1T, w2, W2T);
  scan_build_kernel<<<1, 256, 0, stream>>>(counts, offsets, ntiles, t_e, t_r, t_rend);
  scatter_kernel<<<T_TOK / 256, 256, 0, stream>>>(sel, cursors, offsets, token_list, slot_list);

  hipFuncSetAttribute((const void*)gemm256_kernel<true>,
                      hipFuncAttributeMaxDynamicSharedMemorySize, 131072);
  hipFuncSetAttribute((const void*)gemm256_kernel<false>,
                      hipFuncAttributeMaxDynamicSharedMemorySize, 131072);
  // gemm1: H = gelu(X@W1+b1). grid = 8 xcd * (2 nb-sub * 80 bt)
  gemm256_kernel<true><<<8 * 2 * MAXT, 512, 131072, stream>>>(
      Xb, W1T, b1, token_list, nullptr, t_e, t_r, t_rend, ntiles, H);
  // gemm2: ys = H@W2 scatter. grid = 4 nb * 80 bt
  gemm256_kernel<false><<<4 * MAXT, 512, 131072, stream>>>(
      H, W2T, nullptr, nullptr, slot_list, t_e, t_r, t_rend, ntiles, ys);
  combine_kernel<<<(T_TOK * DMODEL / 8) / 256, 256, 0, stream>>>(ys, wts, sel, b2, out);
}

// Round 17
// 707.435 us; speedup vs baseline: 1.0185x; 1.0010x over previous
//
#include <hip/hip_runtime.h>
#include <stdint.h>

#define T_TOK 8192
#define DMODEL 1024
#define FDIM 4096
#define NEXP 8
#define NROWS 16384      // T_TOK * K
#define MAXT 80          // max 256-row tiles

// prep_kernel block ranges
#define GATE_BLKS 2048                  // T_TOK/4
#define CVT_BLKS  4096                  // T*D/8/256
#define TRW_BLKS  16384                 // 8192 w1-tiles + 8192 w2-tiles (64x64)
#define PREP_BLKS (GATE_BLKS + CVT_BLKS + TRW_BLKS)

typedef __bf16 bf16x8 __attribute__((ext_vector_type(8)));
typedef float f32x4 __attribute__((ext_vector_type(4)));
#define AS1 __attribute__((address_space(1)))
#define AS3 __attribute__((address_space(3)))

__device__ __forceinline__ unsigned short f2bf(float f) {
  union { float f; unsigned u; } v; v.f = f;
  unsigned r = v.u + 0x7fffu + ((v.u >> 16) & 1u);
  return (unsigned short)(r >> 16);
}
__device__ __forceinline__ float bflo(unsigned u) {
  union { unsigned u; float f; } v; v.u = u << 16; return v.f;
}
__device__ __forceinline__ float bfhi(unsigned u) {
  union { unsigned u; float f; } v; v.u = u & 0xffff0000u; return v.f;
}

// ---- fire-and-forget tile transpose: [Kdim][Ndim] f32 -> chunked [kt][n][64]
// Block owns 64k x 64n f32 tile (16 KB LDS). Phase 1: 16x global_load_lds
// (1 KB each, NO VGPR round-trip -> compiler cannot serialize; 16 KB in
// flight per block, 8 blocks/CU = 128 KB/CU). Phase 2: transposed LDS read
// (4-way bank conflict, short) + f32->bf16 cvt + dense stores: each 4-thread
// group emits a full 128B k-line, each wave 2 KB contiguous.
__device__ __forceinline__ void tile_tr_gld(
    const float* __restrict__ in, unsigned short* __restrict__ out,
    int Kdim, int Ndim, int e, int kt, int ng, float* lds)
{
  size_t ebase = (size_t)e * Kdim * Ndim;
  const int tid = threadIdx.x, lane = tid & 63, wave = tid >> 6;
  const int k0 = kt * 64, n0 = ng * 64;
  const int lr = lane >> 4, lc = (lane & 15) * 4;   // row-in-chunk, col (f32)
#pragma unroll
  for (int it = 0; it < 4; ++it) {
    int c = wave * 4 + it;                          // 1KB chunk = 4 k-rows
    const float* src = in + ebase + (size_t)(k0 + c * 4 + lr) * Ndim + n0 + lc;
    __builtin_amdgcn_global_load_lds(
        (const AS1 void*)src, (AS3 void*)((char*)lds + c * 1024), 16, 0, 0);
  }
  asm volatile("s_waitcnt vmcnt(0)" ::: "memory");
  __syncthreads();
  // phase 2: thread -> (n = tid>>2, k16 = (tid&3)*16); 32B dense store
  int n = tid >> 2, k16 = (tid & 3) * 16;
  union { unsigned short h[16]; uint4 q[2]; } pk;
#pragma unroll
  for (int j = 0; j < 16; ++j)
    pk.h[j] = f2bf(lds[(k16 + j) * 64 + n]);
  unsigned short* dst = out + ebase + ((size_t)kt * Ndim + n0 + n) * 64 + k16;
  *(uint4*)dst = pk.q[0];
  *(uint4*)(dst + 8) = pk.q[1];
}

// ---------------- fused prep: gate || f32->bf16 cvt || both W transposes ------
__global__ __launch_bounds__(256) void prep_kernel(
    const float* __restrict__ gx, const float* __restrict__ Wg,
    const float* __restrict__ bg, int* __restrict__ sel,
    float* __restrict__ wts, int* __restrict__ counts,
    const float* __restrict__ inputs, unsigned short* __restrict__ Xb,
    const float* __restrict__ w1, unsigned short* __restrict__ W1T,
    const float* __restrict__ w2, unsigned short* __restrict__ W2T)
{
  __shared__ __align__(16) float tr_lds[64 * 64];   // 16 KB
  int b = blockIdx.x;
  if (b < GATE_BLKS) {
    int t = b * 4 + (threadIdx.x >> 6);
    int lane = threadIdx.x & 63;
    const float* row = gx + (size_t)t * DMODEL;
    float acc[NEXP];
#pragma unroll
    for (int e = 0; e < NEXP; ++e) acc[e] = 0.f;
    for (int d = lane; d < DMODEL; d += 64) {
      float x = row[d];
      const float* wgr = Wg + (size_t)d * NEXP;
#pragma unroll
      for (int e = 0; e < NEXP; ++e) acc[e] += x * wgr[e];
    }
#pragma unroll
    for (int off = 32; off > 0; off >>= 1) {
#pragma unroll
      for (int e = 0; e < NEXP; ++e) acc[e] += __shfl_down(acc[e], off);
    }
    if (lane == 0) {
      float lg[NEXP];
#pragma unroll
      for (int e = 0; e < NEXP; ++e) lg[e] = acc[e] + bg[e];
      int i1 = 0; float v1 = lg[0];
#pragma unroll
      for (int e = 1; e < NEXP; ++e) if (lg[e] > v1) { v1 = lg[e]; i1 = e; }
      int i2 = -1; float v2 = -3.4e38f;
#pragma unroll
      for (int e = 0; e < NEXP; ++e) if (e != i1 && lg[e] > v2) { v2 = lg[e]; i2 = e; }
      float ez = __expf(v2 - v1);           // v2 <= v1
      float s = 1.f / (1.f + ez);
      sel[t*2] = i1; sel[t*2+1] = i2;
      wts[t*2] = s;  wts[t*2+1] = ez * s;
      atomicAdd(&counts[i1], 1);
      atomicAdd(&counts[i2], 1);
    }
  } else if (b < GATE_BLKS + CVT_BLKS) {
    int i = (b - GATE_BLKS) * 256 + threadIdx.x;
    const float4* in4 = (const float4*)inputs;
    float4 v0 = in4[(size_t)i*2], v1 = in4[(size_t)i*2 + 1];
    union { unsigned short u[8]; uint4 q; } r;
    r.u[0]=f2bf(v0.x); r.u[1]=f2bf(v0.y); r.u[2]=f2bf(v0.z); r.u[3]=f2bf(v0.w);
    r.u[4]=f2bf(v1.x); r.u[5]=f2bf(v1.y); r.u[6]=f2bf(v1.z); r.u[7]=f2bf(v1.w);
    ((uint4*)Xb)[i] = r.q;
  } else {
    int bp = b - (GATE_BLKS + CVT_BLKS);   // 0..16383
    if (bp < 8192) {
      // w1 [E][K=1024][N=4096]: 1024 tiles/expert = kt(16) x ng(64)
      int e = bp >> 10, tile = bp & 1023;
      tile_tr_gld(w1, W1T, DMODEL, FDIM, e, tile >> 6, tile & 63, tr_lds);
    } else {
      // w2 [E][K=4096][N=1024]: 1024 tiles/expert = kt(64) x ng(16)
      bp -= 8192;
      int e = bp >> 10, tile = bp & 1023;
      tile_tr_gld(w2, W2T, FDIM, DMODEL, e, tile >> 4, tile & 15, tr_lds);
    }
  }
}

// ---------------- offsets + 256-row tile table (parallel, 1 block) ------------
__global__ __launch_bounds__(256) void scan_build_kernel(
    const int* __restrict__ counts, int* __restrict__ offsets,
    int* __restrict__ ntiles, int* __restrict__ t_e, int* __restrict__ t_r,
    int* __restrict__ t_rend)
{
  __shared__ int sc[8], soff[9], stile[9];
  int tid = threadIdx.x;
  if (tid < 8) sc[tid] = counts[tid];
  __syncthreads();
  if (tid == 0) {
    int off = 0, tl = 0;
#pragma unroll
    for (int e = 0; e < NEXP; ++e) {
      soff[e] = off; stile[e] = tl;
      off += sc[e];
      tl += (sc[e] + 255) >> 8;
    }
    soff[8] = off; stile[8] = tl;
  }
  __syncthreads();
  int ntot = stile[8];
  for (int idx = tid; idx < ntot; idx += 256) {
    int e = 0;
#pragma unroll
    for (int q = 0; q < NEXP; ++q) if (idx >= stile[q + 1]) e = q + 1;
    int r = (idx - stile[e]) * 256;
    t_e[idx] = e; t_r[idx] = soff[e] + r; t_rend[idx] = soff[e] + sc[e];
  }
  if (tid < 9) offsets[tid] = soff[tid];
  if (tid == 0) *ntiles = ntot;
}

// ---------------- scatter: wave-aggregated per-expert atomics -----------------
__global__ __launch_bounds__(256) void scatter_kernel(
    const int* __restrict__ sel, int* __restrict__ cursors,
    const int* __restrict__ offsets, int* __restrict__ token_list,
    int* __restrict__ slot_list)
{
  int t = blockIdx.x * 256 + threadIdx.x;
  int lane = threadIdx.x & 63;
  unsigned long long ltmask = (lane == 63) ? 0x7fffffffffffffffull
                                           : ((1ull << lane) - 1ull);
#pragma unroll
  for (int k = 0; k < 2; ++k) {
    int e = sel[t*2 + k];
#pragma unroll
    for (int ex = 0; ex < NEXP; ++ex) {
      unsigned long long m = __ballot(e == ex);
      if (m == 0ull) continue;
      if (e == ex) {
        int leader = __ffsll((unsigned long long)m) - 1;
        int cnt = __popcll(m);
        int base = 0;
        if (lane == leader) base = atomicAdd(&cursors[ex], cnt);
        base = __shfl(base, leader);
        int r = offsets[ex] + base + __popcll(m & ltmask);
        token_list[r] = t;
        slot_list[r] = t*2 + k;
      }
    }
  }
}

// ---------------- grouped GEMM 256x256, BK=64, 4-phase counted-vmcnt ----------
// Schedule unchanged from R9 (verified). B read from chunked [e][kt][n][64].
template<bool G1>
__global__ __launch_bounds__(512, 2) void gemm256_kernel(
    const unsigned short* __restrict__ A, const unsigned short* __restrict__ B,
    const float* __restrict__ b1, const int* __restrict__ token_list,
    const int* __restrict__ slot_list,
    const int* __restrict__ tile_e, const int* __restrict__ tile_r,
    const int* __restrict__ tile_rend, const int* __restrict__ ntiles,
    unsigned short* __restrict__ outp)
{
  constexpr int KDIM = G1 ? DMODEL : FDIM;   // K extent
  constexpr int NKT  = KDIM / 64;
  constexpr int NOUT = G1 ? FDIM : DMODEL;   // output row width
  constexpr int KTB  = NOUT * 64;            // B k-tile stride (elements)

  int bid = blockIdx.x;
  int nb, bt;
  if constexpr (G1) {                        // 16 nb-panels: pin 2 per XCD, bt-major
    int xcd = bid & 7, idx = bid >> 3;
    nb = xcd * 2 + (idx & 1);
    bt = idx >> 1;
  } else {                                   // 4 nb-panels, bt-major
    nb = bid & 3;
    bt = bid >> 2;
  }
  if (bt >= *ntiles) return;
  const int e = tile_e[bt], row0 = tile_r[bt], rend = tile_rend[bt];
  const int n0 = nb * 256;

  const int tid = threadIdx.x, lane = tid & 63, wave = tid >> 6;
  extern __shared__ __align__(16) char smem[];   // 131072 B

  const int lr8 = lane >> 3, g8 = lane & 7, ch = g8 ^ lr8;

  int mA[2], mB[2];
#pragma unroll
  for (int p = 0; p < 2; ++p)
    mA[p] = (wave < 4) ? (p*64 + wave*16) : (128 + p*64 + (wave-4)*16);
#pragma unroll
  for (int nh = 0; nh < 2; ++nh)
    mB[nh] = (wave >> 1)*64 + nh*32 + (wave & 1)*16;

  const unsigned short* eB = B + (size_t)e * KDIM * NOUT;
  unsigned aoffs[2][2], boffs[2][2];
#pragma unroll
  for (int p = 0; p < 2; ++p)
#pragma unroll
    for (int l = 0; l < 2; ++l) {
      int m = mA[p] + l*8 + lr8;
      int row = row0 + m; if (row > NROWS - 1) row = NROWS - 1;
      int arow = G1 ? token_list[row] : row;
      aoffs[p][l] = (unsigned)arow * KDIM + ch*8;
      int mb = mB[p] + l*8 + lr8;
      boffs[p][l] = (unsigned)((n0 + mb) * 64 + ch*8);
    }

  auto stage_half = [&](int p, int ktn, int bsel) {
    char* base = smem + bsel * 65536;
    if (p < 2) {
      const int kb = ktn * 64;
#pragma unroll
      for (int l = 0; l < 2; ++l)
        __builtin_amdgcn_global_load_lds(
            (const AS1 void*)(A + aoffs[p][l] + kb),
            (AS3 void*)(base + ((mA[p] + l*8) << 7)), 16, 0, 0);
    } else {
      const int nh = p - 2;
      const unsigned short* bk = eB + (size_t)ktn * KTB;
#pragma unroll
      for (int l = 0; l < 2; ++l)
        __builtin_amdgcn_global_load_lds(
            (const AS1 void*)(bk + boffs[nh][l]),
            (AS3 void*)(base + 32768 + ((mB[nh] + l*8) << 7)), 16, 0, 0);
    }
  };

  f32x4 acc[8][4] = {};
  bf16x8 aR[4][2];        // current A-half: 4 row-frags x 2 k-slices
  bf16x8 bR[2][2][2];     // both B-halves: [nh][jj][ks]
  const int wr = wave >> 2, wc = wave & 3;
  const int lm = lane & 15, lk = lane >> 4, l7 = lane & 7;
  const unsigned abase = (unsigned)(wr*128 + lm) * 128;
  const unsigned bbase = 32768u + (unsigned)(wc*64 + lm) * 128;
  const unsigned kx0 = (unsigned)((lk ^ l7) << 4);
  const unsigned kx1 = (unsigned)(((4 + lk) ^ l7) << 4);

  auto rdA = [&](const char* base, int mh) {
#pragma unroll
    for (int i = 0; i < 4; ++i) {
      const char* pA = base + abase + mh*8192 + i*2048;
      aR[i][0] = *(const bf16x8*)(pA + kx0);
      aR[i][1] = *(const bf16x8*)(pA + kx1);
    }
  };
  auto rdB = [&](const char* base, int nh) {
#pragma unroll
    for (int jj = 0; jj < 2; ++jj) {
      const char* pB = base + bbase + nh*4096 + jj*2048;
      bR[nh][jj][0] = *(const bf16x8*)(pB + kx0);
      bR[nh][jj][1] = *(const bf16x8*)(pB + kx1);
    }
  };
  auto mm = [&](int mh, int nh) {
    __builtin_amdgcn_s_setprio(1);
#pragma unroll
    for (int i = 0; i < 4; ++i)
#pragma unroll
      for (int jj = 0; jj < 2; ++jj) {
        acc[mh*4+i][nh*2+jj] = __builtin_amdgcn_mfma_f32_16x16x32_bf16(
            aR[i][0], bR[nh][jj][0], acc[mh*4+i][nh*2+jj], 0, 0, 0);
        acc[mh*4+i][nh*2+jj] = __builtin_amdgcn_mfma_f32_16x16x32_bf16(
            aR[i][1], bR[nh][jj][1], acc[mh*4+i][nh*2+jj], 0, 0, 0);
      }
    __builtin_amdgcn_s_setprio(0);
  };

  // prologue: stage tile 0 halves in consumption order A0,B0,B1,A1
  stage_half(0, 0, 0);
  stage_half(2, 0, 0);
  stage_half(3, 0, 0);
  stage_half(1, 0, 0);

  for (int kt = 0; kt < NKT; ++kt) {
    const int b = kt & 1;
    const int nxt = b ^ 1;
    const char* base = smem + b * 65536;
    const bool pre = (kt + 1 < NKT);
    // ---- P0: quad (0,0); needs A0,B0 ----
    if (pre) {
      stage_half(0, kt + 1, nxt);
      asm volatile("s_waitcnt vmcnt(6)" ::: "memory");
    } else {
      asm volatile("s_waitcnt vmcnt(4)" ::: "memory");
    }
    __builtin_amdgcn_s_barrier();
    __builtin_amdgcn_sched_barrier(0);
    rdA(base, 0); rdB(base, 0);
    asm volatile("s_waitcnt lgkmcnt(0)" ::: "memory");
    __builtin_amdgcn_sched_barrier(0);
    mm(0, 0);
    __builtin_amdgcn_s_barrier();
    // ---- P1: quad (0,1); needs B1 ----
    if (pre) {
      stage_half(2, kt + 1, nxt);
      asm volatile("s_waitcnt vmcnt(6)" ::: "memory");
    } else {
      asm volatile("s_waitcnt vmcnt(2)" ::: "memory");
    }
    __builtin_amdgcn_s_barrier();
    __builtin_amdgcn_sched_barrier(0);
    rdB(base, 1);
    asm volatile("s_waitcnt lgkmcnt(0)" ::: "memory");
    __builtin_amdgcn_sched_barrier(0);
    mm(0, 1);
    __builtin_amdgcn_s_barrier();
    // ---- P2: quad (1,1); needs A1 ----
    if (pre) {
      stage_half(3, kt + 1, nxt);
      asm volatile("s_waitcnt vmcnt(6)" ::: "memory");
    } else {
      asm volatile("s_waitcnt vmcnt(0)" ::: "memory");
    }
    __builtin_amdgcn_s_barrier();
    __builtin_amdgcn_sched_barrier(0);
    rdA(base, 1);
    asm volatile("s_waitcnt lgkmcnt(0)" ::: "memory");
    __builtin_amdgcn_sched_barrier(0);
    mm(1, 1);
    __builtin_amdgcn_s_barrier();
    // ---- P3: quad (1,0); no reads ----
    if (pre) stage_half(1, kt + 1, nxt);
    mm(1, 0);
    __builtin_amdgcn_s_barrier();
    __builtin_amdgcn_sched_barrier(0);
  }

  asm volatile("" ::: "memory");
  float bias[4] = {};
  if constexpr (G1) {
#pragma unroll
    for (int j = 0; j < 4; ++j) bias[j] = b1[(size_t)e * FDIM + n0 + wc*64 + j*16 + lm];
  }

  // epilogue: 8 chunks of 32 rows; [gelu] -> f32 LDS (stride 260) -> bf16 x8
  float* eps = (float*)smem;
#pragma unroll
  for (int c = 0; c < 8; ++c) {
    __syncthreads();
    if (wr == (c >> 2)) {
#pragma unroll
      for (int ii = 0; ii < 2; ++ii) {
        const int mi = (c & 3) * 2 + ii;
#pragma unroll
        for (int j = 0; j < 4; ++j) {
#pragma unroll
          for (int r = 0; r < 4; ++r) {
            float v = acc[mi][j][r];
            if constexpr (G1) {
              v += bias[j];
              float z2 = 1.5957691216f * (v + 0.044715f * v * v * v);
              v = v / (1.f + __expf(-z2));
            }
            eps[(ii*16 + lk*4 + r) * 260 + wc*64 + j*16 + lm] = v;
          }
        }
      }
    }
    __syncthreads();
#pragma unroll
    for (int u = 0; u < 2; ++u) {
      int item = u * 512 + tid;               // 1024 items: 32 rows x 32 octs
      int lrow = item >> 5, c8 = (item & 31) * 8;
      int gr = row0 + c * 32 + lrow;
      if (gr < rend) {
        float4 v0 = *(const float4*)&eps[lrow * 260 + c8];
        float4 v1 = *(const float4*)&eps[lrow * 260 + c8 + 4];
        union { unsigned short u[8]; uint4 q; } pk;
        pk.u[0]=f2bf(v0.x); pk.u[1]=f2bf(v0.y); pk.u[2]=f2bf(v0.z); pk.u[3]=f2bf(v0.w);
        pk.u[4]=f2bf(v1.x); pk.u[5]=f2bf(v1.y); pk.u[6]=f2bf(v1.z); pk.u[7]=f2bf(v1.w);
        size_t orow;
        if constexpr (G1) orow = (size_t)gr * FDIM;
        else              orow = (size_t)slot_list[gr] * DMODEL;
        *(uint4*)(outp + orow + n0 + c8) = pk.q;
      }
    }
  }
}

// ---------------- combine: out = sum_k w_k*(y_k + b2[e_k]) --------------------
__global__ __launch_bounds__(256) void combine_kernel(
    const unsigned short* __restrict__ ys, const float* __restrict__ wts,
    const int* __restrict__ sel, const float* __restrict__ b2,
    float* __restrict__ out)
{
  int i = blockIdx.x * 256 + threadIdx.x;   // over T*D/8
  int t = i >> 7, d8 = i & 127;
  float w0 = wts[t*2], w1 = wts[t*2 + 1];
  int e0 = sel[t*2], e1 = sel[t*2 + 1];
  const uint4* ys4 = (const uint4*)ys;
  uint4 ya = ys4[(size_t)(t*2) * 128 + d8];
  uint4 yb = ys4[(size_t)(t*2 + 1) * 128 + d8];
  const float4* b24 = (const float4*)b2;
  float4 c0a = b24[e0*256 + d8*2], c0b = b24[e0*256 + d8*2 + 1];
  float4 c1a = b24[e1*256 + d8*2], c1b = b24[e1*256 + d8*2 + 1];
  float4 o0, o1;
  o0.x = w0*(bflo(ya.x)+c0a.x) + w1*(bflo(yb.x)+c1a.x);
  o0.y = w0*(bfhi(ya.x)+c0a.y) + w1*(bfhi(yb.x)+c1a.y);
  o0.z = w0*(bflo(ya.y)+c0a.z) + w1*(bflo(yb.y)+c1a.z);
  o0.w = w0*(bfhi(ya.y)+c0a.w) + w1*(bfhi(yb.y)+c1a.w);
  o1.x = w0*(bflo(ya.z)+c0b.x) + w1*(bflo(yb.z)+c1b.x);
  o1.y = w0*(bfhi(ya.z)+c0b.y) + w1*(bfhi(yb.z)+c1b.y);
  o1.z = w0*(bflo(ya.w)+c0b.z) + w1*(bflo(yb.w)+c1b.z);
  o1.w = w0*(bfhi(ya.w)+c0b.w) + w1*(bfhi(yb.w)+c1b.w);
  float4* out4 = (float4*)out;
  out4[(size_t)t * 256 + d8*2]     = o0;
  out4[(size_t)t * 256 + d8*2 + 1] = o1;
}

// ---------------- host ---------------------------------------------------------
extern "C" void kernel_launch(void* const* d_in, const int* in_sizes, int n_in,
                              void* d_out, int out_size, void* d_ws, size_t ws_size,
                              hipStream_t stream)
{
  const float* gate_inputs = (const float*)d_in[0];
  const float* inputs      = (const float*)d_in[1];
  const float* Wg          = (const float*)d_in[2];
  const float* bg          = (const float*)d_in[3];
  const float* w1          = (const float*)d_in[4];
  const float* b1          = (const float*)d_in[5];
  const float* w2          = (const float*)d_in[6];
  const float* b2          = (const float*)d_in[7];
  float* out = (float*)d_out;

  char* ws = (char*)d_ws;
  size_t o = 0;
  auto carve = [&](size_t bytes) { void* p = ws + o; o += (bytes + 255) & ~(size_t)255; return p; };
  unsigned short* Xb  = (unsigned short*)carve((size_t)T_TOK * DMODEL * 2);
  unsigned short* W1T = (unsigned short*)carve((size_t)NEXP * FDIM * DMODEL * 2);
  unsigned short* W2T = (unsigned short*)carve((size_t)NEXP * DMODEL * FDIM * 2);
  unsigned short* H   = (unsigned short*)carve((size_t)NROWS * FDIM * 2);
  unsigned short* ys  = (unsigned short*)carve((size_t)NROWS * DMODEL * 2);
  int*   sel          = (int*)carve((size_t)NROWS * 4);
  float* wts          = (float*)carve((size_t)NROWS * 4);
  int*   token_list   = (int*)carve((size_t)(NROWS + 256) * 4);
  int*   slot_list    = (int*)carve((size_t)(NROWS + 256) * 4);
  int*   ctrl         = (int*)carve(4096);
  int* counts  = ctrl;            // 8
  int* cursors = ctrl + 8;        // 8
  int* offsets = ctrl + 16;       // 9
  int* ntiles  = ctrl + 28;       // 1
  int* t_e     = ctrl + 32;
  int* t_r     = ctrl + 32 + MAXT;
  int* t_rend  = ctrl + 32 + 2 * MAXT;

  hipMemsetAsync(counts, 0, 64, stream);  // counts + cursors

  prep_kernel<<<PREP_BLKS, 256, 0, stream>>>(
      gate_inputs, Wg, bg, sel, wts, counts,
      inputs, Xb, w1, W1T, w2, W2T);
  scan_build_kernel<<<1, 256, 0, stream>>>(counts, offsets, ntiles, t_e, t_r, t_rend);
  scatter_kernel<<<T_TOK / 256, 256, 0, stream>>>(sel, cursors, offsets, token_list, slot_list);

  hipFuncSetAttribute((const void*)gemm256_kernel<true>,
                      hipFuncAttributeMaxDynamicSharedMemorySize, 131072);
  hipFuncSetAttribute((const void*)gemm256_kernel<false>,
                      hipFuncAttributeMaxDynamicSharedMemorySize, 131072);
  // gemm1: H = gelu(X@W1+b1). grid = 8 xcd * (2 nb-sub * 80 bt)
  gemm256_kernel<true><<<8 * 2 * MAXT, 512, 131072, stream>>>(
      Xb, W1T, b1, token_list, nullptr, t_e, t_r, t_rend, ntiles, H);
  // gemm2: ys = H@W2 scatter. grid = 4 nb * 80 bt
  gemm256_kernel<false><<<4 * MAXT, 512, 131072, stream>>>(
      H, W2T, nullptr, nullptr, slot_list, t_e, t_r, t_rend, ntiles, ys);
  combine_kernel<<<(T_TOK * DMODEL / 8) / 256, 256, 0, stream>>>(ys, wts, sel, b2, out);
}

// Round 18
// 590.469 us; speedup vs baseline: 1.2203x; 1.1981x over previous
//
#include <hip/hip_runtime.h>
#include <stdint.h>

#define T_TOK 8192
#define DMODEL 1024
#define FDIM 4096
#define NEXP 8
#define NROWS 16384      // T_TOK * K
#define MAXT 80          // max 256-row tiles

// prep_kernel block ranges
#define GATE_BLKS 2048                  // T_TOK/4
#define CVT_BLKS  4096                  // T*D/8/256
#define TRP_BLKS  2048                  // 1024 w1-groups + 1024 w2-groups (8 tiles each)
#define PREP_BLKS (GATE_BLKS + CVT_BLKS + TRP_BLKS)

typedef __bf16 bf16x8 __attribute__((ext_vector_type(8)));
typedef float f32x4 __attribute__((ext_vector_type(4)));
#define AS1 __attribute__((address_space(1)))
#define AS3 __attribute__((address_space(3)))

__device__ __forceinline__ unsigned short f2bf(float f) {
  union { float f; unsigned u; } v; v.f = f;
  unsigned r = v.u + 0x7fffu + ((v.u >> 16) & 1u);
  return (unsigned short)(r >> 16);
}
__device__ __forceinline__ float bflo(unsigned u) {
  union { unsigned u; float f; } v; v.u = u << 16; return v.f;
}
__device__ __forceinline__ float bfhi(unsigned u) {
  union { unsigned u; float f; } v; v.u = u & 0xffff0000u; return v.f;
}

// ---- pipelined tile transpose: [Kdim][Ndim] f32 -> chunked [kt][n][64] bf16
// Block owns 8 consecutive-ng 64x64 tiles, double-buffered 2x16KB LDS.
// Per iter: stage(i+1, buf^1) via fire-and-forget global_load_lds ->
// vmcnt(4) [counted per-wave: tile i's 4 loads done, i+1's in flight] ->
// barrier -> phase2 (LDS col read + cvt + 32B dense store) -> barrier.
// HBM latency hides under phase2; block touches the SAME 64 DRAM rows for
// all 8 tiles (marching right 256B per tile) -> page-friendly.
__device__ __forceinline__ void tile_tr_pipe(
    const float* __restrict__ in, unsigned short* __restrict__ out,
    int Kdim, int Ndim, int e, int kt, int ng0, float* lds)
{
  size_t ebase = (size_t)e * Kdim * Ndim;
  const int tid = threadIdx.x, lane = tid & 63, wave = tid >> 6;
  const int lr = lane >> 4, lc = (lane & 15) * 4;
  auto stage = [&](int i, int b) {
    const int n0 = (ng0 + i) * 64;
#pragma unroll
    for (int it = 0; it < 4; ++it) {
      int c = wave * 4 + it;                        // 1KB chunk = 4 k-rows
      const float* src = in + ebase + (size_t)(kt * 64 + c * 4 + lr) * Ndim + n0 + lc;
      __builtin_amdgcn_global_load_lds(
          (const AS1 void*)src,
          (AS3 void*)((char*)lds + b * 16384 + c * 1024), 16, 0, 0);
    }
  };
  stage(0, 0);
  for (int i = 0; i < 8; ++i) {
    const int b = i & 1;
    if (i + 1 < 8) {
      stage(i + 1, b ^ 1);
      asm volatile("s_waitcnt vmcnt(4)" ::: "memory");
    } else {
      asm volatile("s_waitcnt vmcnt(0)" ::: "memory");
    }
    __syncthreads();
    const float* L = lds + b * 4096;
    int n = tid >> 2, k16 = (tid & 3) * 16;
    union { unsigned short h[16]; uint4 q[2]; } pk;
#pragma unroll
    for (int j = 0; j < 16; ++j)
      pk.h[j] = f2bf(L[(k16 + j) * 64 + n]);
    unsigned short* dst = out + ebase + ((size_t)kt * Ndim + (ng0 + i) * 64 + n) * 64 + k16;
    *(uint4*)dst = pk.q[0];
    *(uint4*)(dst + 8) = pk.q[1];
    __syncthreads();                                // phase2 done before buf reuse
  }
}

// ---------------- fused prep: gate || f32->bf16 cvt || both W transposes ------
__global__ __launch_bounds__(256) void prep_kernel(
    const float* __restrict__ gx, const float* __restrict__ Wg,
    const float* __restrict__ bg, int* __restrict__ sel,
    float* __restrict__ wts,
    const float* __restrict__ inputs, unsigned short* __restrict__ Xb,
    const float* __restrict__ w1, unsigned short* __restrict__ W1T,
    const float* __restrict__ w2, unsigned short* __restrict__ W2T)
{
  __shared__ __align__(16) float tr_lds[2 * 64 * 64];   // 32 KB dbuf
  int b = blockIdx.x;
  if (b < GATE_BLKS) {
    int t = b * 4 + (threadIdx.x >> 6);
    int lane = threadIdx.x & 63;
    const float* row = gx + (size_t)t * DMODEL;
    float acc[NEXP];
#pragma unroll
    for (int e = 0; e < NEXP; ++e) acc[e] = 0.f;
    for (int d = lane; d < DMODEL; d += 64) {
      float x = row[d];
      const float* wgr = Wg + (size_t)d * NEXP;
#pragma unroll
      for (int e = 0; e < NEXP; ++e) acc[e] += x * wgr[e];
    }
#pragma unroll
    for (int off = 32; off > 0; off >>= 1) {
#pragma unroll
      for (int e = 0; e < NEXP; ++e) acc[e] += __shfl_down(acc[e], off);
    }
    if (lane == 0) {
      float lg[NEXP];
#pragma unroll
      for (int e = 0; e < NEXP; ++e) lg[e] = acc[e] + bg[e];
      int i1 = 0; float v1 = lg[0];
#pragma unroll
      for (int e = 1; e < NEXP; ++e) if (lg[e] > v1) { v1 = lg[e]; i1 = e; }
      int i2 = -1; float v2 = -3.4e38f;
#pragma unroll
      for (int e = 0; e < NEXP; ++e) if (e != i1 && lg[e] > v2) { v2 = lg[e]; i2 = e; }
      float ez = __expf(v2 - v1);           // v2 <= v1
      float s = 1.f / (1.f + ez);
      sel[t*2] = i1; sel[t*2+1] = i2;
      wts[t*2] = s;  wts[t*2+1] = ez * s;   // no atomics: counts from sel in scan
    }
  } else if (b < GATE_BLKS + CVT_BLKS) {
    int i = (b - GATE_BLKS) * 256 + threadIdx.x;
    const float4* in4 = (const float4*)inputs;
    float4 v0 = in4[(size_t)i*2], v1 = in4[(size_t)i*2 + 1];
    union { unsigned short u[8]; uint4 q; } r;
    r.u[0]=f2bf(v0.x); r.u[1]=f2bf(v0.y); r.u[2]=f2bf(v0.z); r.u[3]=f2bf(v0.w);
    r.u[4]=f2bf(v1.x); r.u[5]=f2bf(v1.y); r.u[6]=f2bf(v1.z); r.u[7]=f2bf(v1.w);
    ((uint4*)Xb)[i] = r.q;
  } else {
    int bp = b - (GATE_BLKS + CVT_BLKS);   // 0..2047
    if (bp < 1024) {
      // w1 [E][K=1024][N=4096]: 128 groups/expert = kt(16) x nggrp(8)
      int e = bp >> 7, rem = bp & 127;
      tile_tr_pipe(w1, W1T, DMODEL, FDIM, e, rem >> 3, (rem & 7) * 8, tr_lds);
    } else {
      // w2 [E][K=4096][N=1024]: 128 groups/expert = kt(64) x nggrp(2)
      bp -= 1024;
      int e = bp >> 7, rem = bp & 127;
      tile_tr_pipe(w2, W2T, FDIM, DMODEL, e, rem >> 1, (rem & 1) * 8, tr_lds);
    }
  }
}

// ---------------- hist(sel) + offsets + 256-row tile table (1 block) ----------
__global__ __launch_bounds__(256) void scan_build_kernel(
    const int* __restrict__ sel, int* __restrict__ offsets,
    int* __restrict__ ntiles, int* __restrict__ t_e, int* __restrict__ t_r,
    int* __restrict__ t_rend)
{
  __shared__ int sc[8], soff[9], stile[9];
  int tid = threadIdx.x;
  if (tid < 8) sc[tid] = 0;
  __syncthreads();
  int cnt[NEXP];
#pragma unroll
  for (int e = 0; e < NEXP; ++e) cnt[e] = 0;
  for (int i = tid; i < NROWS; i += 256) {
    int v = sel[i];
#pragma unroll
    for (int e = 0; e < NEXP; ++e) cnt[e] += (v == e) ? 1 : 0;
  }
#pragma unroll
  for (int e = 0; e < NEXP; ++e) if (cnt[e]) atomicAdd(&sc[e], cnt[e]);
  __syncthreads();
  if (tid == 0) {
    int off = 0, tl = 0;
#pragma unroll
    for (int e = 0; e < NEXP; ++e) {
      soff[e] = off; stile[e] = tl;
      off += sc[e];
      tl += (sc[e] + 255) >> 8;
    }
    soff[8] = off; stile[8] = tl;
  }
  __syncthreads();
  int ntot = stile[8];
  for (int idx = tid; idx < ntot; idx += 256) {
    int e = 0;
#pragma unroll
    for (int q = 0; q < NEXP; ++q) if (idx >= stile[q + 1]) e = q + 1;
    int r = (idx - stile[e]) * 256;
    t_e[idx] = e; t_r[idx] = soff[e] + r; t_rend[idx] = soff[e] + sc[e];
  }
  if (tid < 9) offsets[tid] = soff[tid];
  if (tid == 0) *ntiles = ntot;
}

// ---------------- scatter: wave-aggregated per-expert atomics -----------------
__global__ __launch_bounds__(256) void scatter_kernel(
    const int* __restrict__ sel, int* __restrict__ cursors,
    const int* __restrict__ offsets, int* __restrict__ token_list,
    int* __restrict__ slot_list)
{
  int t = blockIdx.x * 256 + threadIdx.x;
  int lane = threadIdx.x & 63;
  unsigned long long ltmask = (lane == 63) ? 0x7fffffffffffffffull
                                           : ((1ull << lane) - 1ull);
#pragma unroll
  for (int k = 0; k < 2; ++k) {
    int e = sel[t*2 + k];
#pragma unroll
    for (int ex = 0; ex < NEXP; ++ex) {
      unsigned long long m = __ballot(e == ex);
      if (m == 0ull) continue;
      if (e == ex) {
        int leader = __ffsll((unsigned long long)m) - 1;
        int cnt = __popcll(m);
        int base = 0;
        if (lane == leader) base = atomicAdd(&cursors[ex], cnt);
        base = __shfl(base, leader);
        int r = offsets[ex] + base + __popcll(m & ltmask);
        token_list[r] = t;
        slot_list[r] = t*2 + k;
      }
    }
  }
}

// ---------------- grouped GEMM 256x256, BK=64, 4-phase counted-vmcnt ----------
// Schedule unchanged from R9 (verified). B read from chunked [e][kt][n][64].
template<bool G1>
__global__ __launch_bounds__(512, 2) void gemm256_kernel(
    const unsigned short* __restrict__ A, const unsigned short* __restrict__ B,
    const float* __restrict__ b1, const int* __restrict__ token_list,
    const int* __restrict__ slot_list,
    const int* __restrict__ tile_e, const int* __restrict__ tile_r,
    const int* __restrict__ tile_rend, const int* __restrict__ ntiles,
    unsigned short* __restrict__ outp)
{
  constexpr int KDIM = G1 ? DMODEL : FDIM;   // K extent
  constexpr int NKT  = KDIM / 64;
  constexpr int NOUT = G1 ? FDIM : DMODEL;   // output row width
  constexpr int KTB  = NOUT * 64;            // B k-tile stride (elements)

  int bid = blockIdx.x;
  int nb, bt;
  if constexpr (G1) {                        // 16 nb-panels: pin 2 per XCD, bt-major
    int xcd = bid & 7, idx = bid >> 3;
    nb = xcd * 2 + (idx & 1);
    bt = idx >> 1;
  } else {                                   // 4 nb-panels, bt-major
    nb = bid & 3;
    bt = bid >> 2;
  }
  if (bt >= *ntiles) return;
  const int e = tile_e[bt], row0 = tile_r[bt], rend = tile_rend[bt];
  const int n0 = nb * 256;

  const int tid = threadIdx.x, lane = tid & 63, wave = tid >> 6;
  extern __shared__ __align__(16) char smem[];   // 131072 B

  const int lr8 = lane >> 3, g8 = lane & 7, ch = g8 ^ lr8;

  int mA[2], mB[2];
#pragma unroll
  for (int p = 0; p < 2; ++p)
    mA[p] = (wave < 4) ? (p*64 + wave*16) : (128 + p*64 + (wave-4)*16);
#pragma unroll
  for (int nh = 0; nh < 2; ++nh)
    mB[nh] = (wave >> 1)*64 + nh*32 + (wave & 1)*16;

  const unsigned short* eB = B + (size_t)e * KDIM * NOUT;
  unsigned aoffs[2][2], boffs[2][2];
#pragma unroll
  for (int p = 0; p < 2; ++p)
#pragma unroll
    for (int l = 0; l < 2; ++l) {
      int m = mA[p] + l*8 + lr8;
      int row = row0 + m; if (row > NROWS - 1) row = NROWS - 1;
      int arow = G1 ? token_list[row] : row;
      aoffs[p][l] = (unsigned)arow * KDIM + ch*8;
      int mb = mB[p] + l*8 + lr8;
      boffs[p][l] = (unsigned)((n0 + mb) * 64 + ch*8);
    }

  auto stage_half = [&](int p, int ktn, int bsel) {
    char* base = smem + bsel * 65536;
    if (p < 2) {
      const int kb = ktn * 64;
#pragma unroll
      for (int l = 0; l < 2; ++l)
        __builtin_amdgcn_global_load_lds(
            (const AS1 void*)(A + aoffs[p][l] + kb),
            (AS3 void*)(base + ((mA[p] + l*8) << 7)), 16, 0, 0);
    } else {
      const int nh = p - 2;
      const unsigned short* bk = eB + (size_t)ktn * KTB;
#pragma unroll
      for (int l = 0; l < 2; ++l)
        __builtin_amdgcn_global_load_lds(
            (const AS1 void*)(bk + boffs[nh][l]),
            (AS3 void*)(base + 32768 + ((mB[nh] + l*8) << 7)), 16, 0, 0);
    }
  };

  f32x4 acc[8][4] = {};
  bf16x8 aR[4][2];        // current A-half: 4 row-frags x 2 k-slices
  bf16x8 bR[2][2][2];     // both B-halves: [nh][jj][ks]
  const int wr = wave >> 2, wc = wave & 3;
  const int lm = lane & 15, lk = lane >> 4, l7 = lane & 7;
  const unsigned abase = (unsigned)(wr*128 + lm) * 128;
  const unsigned bbase = 32768u + (unsigned)(wc*64 + lm) * 128;
  const unsigned kx0 = (unsigned)((lk ^ l7) << 4);
  const unsigned kx1 = (unsigned)(((4 + lk) ^ l7) << 4);

  auto rdA = [&](const char* base, int mh) {
#pragma unroll
    for (int i = 0; i < 4; ++i) {
      const char* pA = base + abase + mh*8192 + i*2048;
      aR[i][0] = *(const bf16x8*)(pA + kx0);
      aR[i][1] = *(const bf16x8*)(pA + kx1);
    }
  };
  auto rdB = [&](const char* base, int nh) {
#pragma unroll
    for (int jj = 0; jj < 2; ++jj) {
      const char* pB = base + bbase + nh*4096 + jj*2048;
      bR[nh][jj][0] = *(const bf16x8*)(pB + kx0);
      bR[nh][jj][1] = *(const bf16x8*)(pB + kx1);
    }
  };
  auto mm = [&](int mh, int nh) {
    __builtin_amdgcn_s_setprio(1);
#pragma unroll
    for (int i = 0; i < 4; ++i)
#pragma unroll
      for (int jj = 0; jj < 2; ++jj) {
        acc[mh*4+i][nh*2+jj] = __builtin_amdgcn_mfma_f32_16x16x32_bf16(
            aR[i][0], bR[nh][jj][0], acc[mh*4+i][nh*2+jj], 0, 0, 0);
        acc[mh*4+i][nh*2+jj] = __builtin_amdgcn_mfma_f32_16x16x32_bf16(
            aR[i][1], bR[nh][jj][1], acc[mh*4+i][nh*2+jj], 0, 0, 0);
      }
    __builtin_amdgcn_s_setprio(0);
  };

  // prologue: stage tile 0 halves in consumption order A0,B0,B1,A1
  stage_half(0, 0, 0);
  stage_half(2, 0, 0);
  stage_half(3, 0, 0);
  stage_half(1, 0, 0);

  for (int kt = 0; kt < NKT; ++kt) {
    const int b = kt & 1;
    const int nxt = b ^ 1;
    const char* base = smem + b * 65536;
    const bool pre = (kt + 1 < NKT);
    // ---- P0: quad (0,0); needs A0,B0 ----
    if (pre) {
      stage_half(0, kt + 1, nxt);
      asm volatile("s_waitcnt vmcnt(6)" ::: "memory");
    } else {
      asm volatile("s_waitcnt vmcnt(4)" ::: "memory");
    }
    __builtin_amdgcn_s_barrier();
    __builtin_amdgcn_sched_barrier(0);
    rdA(base, 0); rdB(base, 0);
    asm volatile("s_waitcnt lgkmcnt(0)" ::: "memory");
    __builtin_amdgcn_sched_barrier(0);
    mm(0, 0);
    __builtin_amdgcn_s_barrier();
    // ---- P1: quad (0,1); needs B1 ----
    if (pre) {
      stage_half(2, kt + 1, nxt);
      asm volatile("s_waitcnt vmcnt(6)" ::: "memory");
    } else {
      asm volatile("s_waitcnt vmcnt(2)" ::: "memory");
    }
    __builtin_amdgcn_s_barrier();
    __builtin_amdgcn_sched_barrier(0);
    rdB(base, 1);
    asm volatile("s_waitcnt lgkmcnt(0)" ::: "memory");
    __builtin_amdgcn_sched_barrier(0);
    mm(0, 1);
    __builtin_amdgcn_s_barrier();
    // ---- P2: quad (1,1); needs A1 ----
    if (pre) {
      stage_half(3, kt + 1, nxt);
      asm volatile("s_waitcnt vmcnt(6)" ::: "memory");
    } else {
      asm volatile("s_waitcnt vmcnt(0)" ::: "memory");
    }
    __builtin_amdgcn_s_barrier();
    __builtin_amdgcn_sched_barrier(0);
    rdA(base, 1);
    asm volatile("s_waitcnt lgkmcnt(0)" ::: "memory");
    __builtin_amdgcn_sched_barrier(0);
    mm(1, 1);
    __builtin_amdgcn_s_barrier();
    // ---- P3: quad (1,0); no reads ----
    if (pre) stage_half(1, kt + 1, nxt);
    mm(1, 0);
    __builtin_amdgcn_s_barrier();
    __builtin_amdgcn_sched_barrier(0);
  }

  asm volatile("" ::: "memory");
  float bias[4] = {};
  if constexpr (G1) {
#pragma unroll
    for (int j = 0; j < 4; ++j) bias[j] = b1[(size_t)e * FDIM + n0 + wc*64 + j*16 + lm];
  }

  // epilogue: 8 chunks of 32 rows; [gelu] -> f32 LDS (stride 260) -> bf16 x8
  float* eps = (float*)smem;
#pragma unroll
  for (int c = 0; c < 8; ++c) {
    __syncthreads();
    if (wr == (c >> 2)) {
#pragma unroll
      for (int ii = 0; ii < 2; ++ii) {
        const int mi = (c & 3) * 2 + ii;
#pragma unroll
        for (int j = 0; j < 4; ++j) {
#pragma unroll
          for (int r = 0; r < 4; ++r) {
            float v = acc[mi][j][r];
            if constexpr (G1) {
              v += bias[j];
              float z2 = 1.5957691216f * (v + 0.044715f * v * v * v);
              v = v / (1.f + __expf(-z2));
            }
            eps[(ii*16 + lk*4 + r) * 260 + wc*64 + j*16 + lm] = v;
          }
        }
      }
    }
    __syncthreads();
#pragma unroll
    for (int u = 0; u < 2; ++u) {
      int item = u * 512 + tid;               // 1024 items: 32 rows x 32 octs
      int lrow = item >> 5, c8 = (item & 31) * 8;
      int gr = row0 + c * 32 + lrow;
      if (gr < rend) {
        float4 v0 = *(const float4*)&eps[lrow * 260 + c8];
        float4 v1 = *(const float4*)&eps[lrow * 260 + c8 + 4];
        union { unsigned short u[8]; uint4 q; } pk;
        pk.u[0]=f2bf(v0.x); pk.u[1]=f2bf(v0.y); pk.u[2]=f2bf(v0.z); pk.u[3]=f2bf(v0.w);
        pk.u[4]=f2bf(v1.x); pk.u[5]=f2bf(v1.y); pk.u[6]=f2bf(v1.z); pk.u[7]=f2bf(v1.w);
        size_t orow;
        if constexpr (G1) orow = (size_t)gr * FDIM;
        else              orow = (size_t)slot_list[gr] * DMODEL;
        *(uint4*)(outp + orow + n0 + c8) = pk.q;
      }
    }
  }
}

// ---------------- combine: out = sum_k w_k*(y_k + b2[e_k]) --------------------
__global__ __launch_bounds__(256) void combine_kernel(
    const unsigned short* __restrict__ ys, const float* __restrict__ wts,
    const int* __restrict__ sel, const float* __restrict__ b2,
    float* __restrict__ out)
{
  int i = blockIdx.x * 256 + threadIdx.x;   // over T*D/8
  int t = i >> 7, d8 = i & 127;
  float w0 = wts[t*2], w1 = wts[t*2 + 1];
  int e0 = sel[t*2], e1 = sel[t*2 + 1];
  const uint4* ys4 = (const uint4*)ys;
  uint4 ya = ys4[(size_t)(t*2) * 128 + d8];
  uint4 yb = ys4[(size_t)(t*2 + 1) * 128 + d8];
  const float4* b24 = (const float4*)b2;
  float4 c0a = b24[e0*256 + d8*2], c0b = b24[e0*256 + d8*2 + 1];
  float4 c1a = b24[e1*256 + d8*2], c1b = b24[e1*256 + d8*2 + 1];
  float4 o0, o1;
  o0.x = w0*(bflo(ya.x)+c0a.x) + w1*(bflo(yb.x)+c1a.x);
  o0.y = w0*(bfhi(ya.x)+c0a.y) + w1*(bfhi(yb.x)+c1a.y);
  o0.z = w0*(bflo(ya.y)+c0a.z) + w1*(bflo(yb.y)+c1a.z);
  o0.w = w0*(bfhi(ya.y)+c0a.w) + w1*(bfhi(yb.y)+c1a.w);
  o1.x = w0*(bflo(ya.z)+c0b.x) + w1*(bflo(yb.z)+c1b.x);
  o1.y = w0*(bfhi(ya.z)+c0b.y) + w1*(bfhi(yb.z)+c1b.y);
  o1.z = w0*(bflo(ya.w)+c0b.z) + w1*(bflo(yb.w)+c1b.z);
  o1.w = w0*(bfhi(ya.w)+c0b.w) + w1*(bfhi(yb.w)+c1b.w);
  float4* out4 = (float4*)out;
  out4[(size_t)t * 256 + d8*2]     = o0;
  out4[(size_t)t * 256 + d8*2 + 1] = o1;
}

// ---------------- host ---------------------------------------------------------
extern "C" void kernel_launch(void* const* d_in, const int* in_sizes, int n_in,
                              void* d_out, int out_size, void* d_ws, size_t ws_size,
                              hipStream_t stream)
{
  const float* gate_inputs = (const float*)d_in[0];
  const float* inputs      = (const float*)d_in[1];
  const float* Wg          = (const float*)d_in[2];
  const float* bg          = (const float*)d_in[3];
  const float* w1          = (const float*)d_in[4];
  const float* b1          = (const float*)d_in[5];
  const float* w2          = (const float*)d_in[6];
  const float* b2          = (const float*)d_in[7];
  float* out = (float*)d_out;

  char* ws = (char*)d_ws;
  size_t o = 0;
  auto carve = [&](size_t bytes) { void* p = ws + o; o += (bytes + 255) & ~(size_t)255; return p; };
  unsigned short* Xb  = (unsigned short*)carve((size_t)T_TOK * DMODEL * 2);
  unsigned short* W1T = (unsigned short*)carve((size_t)NEXP * FDIM * DMODEL * 2);
  unsigned short* W2T = (unsigned short*)carve((size_t)NEXP * DMODEL * FDIM * 2);
  unsigned short* H   = (unsigned short*)carve((size_t)NROWS * FDIM * 2);
  unsigned short* ys  = (unsigned short*)carve((size_t)NROWS * DMODEL * 2);
  int*   sel          = (int*)carve((size_t)NROWS * 4);
  float* wts          = (float*)carve((size_t)NROWS * 4);
  int*   token_list   = (int*)carve((size_t)(NROWS + 256) * 4);
  int*   slot_list    = (int*)carve((size_t)(NROWS + 256) * 4);
  int*   ctrl         = (int*)carve(4096);
  int* cursors = ctrl + 8;        // 8
  int* offsets = ctrl + 16;       // 9
  int* ntiles  = ctrl + 28;       // 1
  int* t_e     = ctrl + 32;
  int* t_r     = ctrl + 32 + MAXT;
  int* t_rend  = ctrl + 32 + 2 * MAXT;

  hipMemsetAsync(ctrl, 0, 64, stream);  // cursors

  prep_kernel<<<PREP_BLKS, 256, 0, stream>>>(
      gate_inputs, Wg, bg, sel, wts,
      inputs, Xb, w1, W1T, w2, W2T);
  scan_build_kernel<<<1, 256, 0, stream>>>(sel, offsets, ntiles, t_e, t_r, t_rend);
  scatter_kernel<<<T_TOK / 256, 256, 0, stream>>>(sel, cursors, offsets, token_list, slot_list);

  hipFuncSetAttribute((const void*)gemm256_kernel<true>,
                      hipFuncAttributeMaxDynamicSharedMemorySize, 131072);
  hipFuncSetAttribute((const void*)gemm256_kernel<false>,
                      hipFuncAttributeMaxDynamicSharedMemorySize, 131072);
  // gemm1: H = gelu(X@W1+b1). grid = 8 xcd * (2 nb-sub * 80 bt)
  gemm256_kernel<true><<<8 * 2 * MAXT, 512, 131072, stream>>>(
      Xb, W1T, b1, token_list, nullptr, t_e, t_r, t_rend, ntiles, H);
  // gemm2: ys = H@W2 scatter. grid = 4 nb * 80 bt
  gemm256_kernel<false><<<4 * MAXT, 512, 131072, stream>>>(
      H, W2T, nullptr, nullptr, slot_list, t_e, t_r, t_rend, ntiles, ys);
  combine_kernel<<<(T_TOK * DMODEL / 8) / 256, 256, 0, stream>>>(ys, wts, sel, b2, out);
}

// Round 19
// 586.075 us; speedup vs baseline: 1.2294x; 1.0075x over previous
//
#include <hip/hip_runtime.h>
#include <stdint.h>

#define T_TOK 8192
#define DMODEL 1024
#define FDIM 4096
#define NEXP 8
#define NROWS 16384      // T_TOK * K
#define MAXT 80          // max 256-row tiles

// prep_kernel block ranges
#define GATE_BLKS 2048                  // T_TOK/4
#define CVT_BLKS  4096                  // T*D/8/256
#define TRP_BLKS  2048                  // 1024 w1-groups + 1024 w2-groups (8 tiles each)
#define PREP_BLKS (GATE_BLKS + CVT_BLKS + TRP_BLKS)

typedef __bf16 bf16x8 __attribute__((ext_vector_type(8)));
typedef float f32x4 __attribute__((ext_vector_type(4)));
#define AS1 __attribute__((address_space(1)))
#define AS3 __attribute__((address_space(3)))

__device__ __forceinline__ unsigned short f2bf(float f) {
  union { float f; unsigned u; } v; v.f = f;
  unsigned r = v.u + 0x7fffu + ((v.u >> 16) & 1u);
  return (unsigned short)(r >> 16);
}
__device__ __forceinline__ float bflo(unsigned u) {
  union { unsigned u; float f; } v; v.u = u << 16; return v.f;
}
__device__ __forceinline__ float bfhi(unsigned u) {
  union { unsigned u; float f; } v; v.u = u & 0xffff0000u; return v.f;
}

// ---- pipelined tile transpose (verified R18): f32 -> chunked [kt][n][64] bf16
__device__ __forceinline__ void tile_tr_pipe(
    const float* __restrict__ in, unsigned short* __restrict__ out,
    int Kdim, int Ndim, int e, int kt, int ng0, float* lds)
{
  size_t ebase = (size_t)e * Kdim * Ndim;
  const int tid = threadIdx.x, lane = tid & 63, wave = tid >> 6;
  const int lr = lane >> 4, lc = (lane & 15) * 4;
  auto stage = [&](int i, int b) {
    const int n0 = (ng0 + i) * 64;
#pragma unroll
    for (int it = 0; it < 4; ++it) {
      int c = wave * 4 + it;                        // 1KB chunk = 4 k-rows
      const float* src = in + ebase + (size_t)(kt * 64 + c * 4 + lr) * Ndim + n0 + lc;
      __builtin_amdgcn_global_load_lds(
          (const AS1 void*)src,
          (AS3 void*)((char*)lds + b * 16384 + c * 1024), 16, 0, 0);
    }
  };
  stage(0, 0);
  for (int i = 0; i < 8; ++i) {
    const int b = i & 1;
    if (i + 1 < 8) {
      stage(i + 1, b ^ 1);
      asm volatile("s_waitcnt vmcnt(4)" ::: "memory");
    } else {
      asm volatile("s_waitcnt vmcnt(0)" ::: "memory");
    }
    __syncthreads();
    const float* L = lds + b * 4096;
    int n = tid >> 2, k16 = (tid & 3) * 16;
    union { unsigned short h[16]; uint4 q[2]; } pk;
#pragma unroll
    for (int j = 0; j < 16; ++j)
      pk.h[j] = f2bf(L[(k16 + j) * 64 + n]);
    unsigned short* dst = out + ebase + ((size_t)kt * Ndim + (ng0 + i) * 64 + n) * 64 + k16;
    *(uint4*)dst = pk.q[0];
    *(uint4*)(dst + 8) = pk.q[1];
    __syncthreads();                                // phase2 done before buf reuse
  }
}

// ---------------- fused prep: gate || f32->bf16 cvt || both W transposes ------
__global__ __launch_bounds__(256) void prep_kernel(
    const float* __restrict__ gx, const float* __restrict__ Wg,
    const float* __restrict__ bg, int* __restrict__ sel,
    float* __restrict__ wts,
    const float* __restrict__ inputs, unsigned short* __restrict__ Xb,
    const float* __restrict__ w1, unsigned short* __restrict__ W1T,
    const float* __restrict__ w2, unsigned short* __restrict__ W2T)
{
  __shared__ __align__(16) float tr_lds[2 * 64 * 64];   // 32 KB dbuf
  int b = blockIdx.x;
  if (b < GATE_BLKS) {
    int t = b * 4 + (threadIdx.x >> 6);
    int lane = threadIdx.x & 63;
    const float* row = gx + (size_t)t * DMODEL;
    float acc[NEXP];
#pragma unroll
    for (int e = 0; e < NEXP; ++e) acc[e] = 0.f;
    for (int d = lane; d < DMODEL; d += 64) {
      float x = row[d];
      const float* wgr = Wg + (size_t)d * NEXP;
#pragma unroll
      for (int e = 0; e < NEXP; ++e) acc[e] += x * wgr[e];
    }
#pragma unroll
    for (int off = 32; off > 0; off >>= 1) {
#pragma unroll
      for (int e = 0; e < NEXP; ++e) acc[e] += __shfl_down(acc[e], off);
    }
    if (lane == 0) {
      float lg[NEXP];
#pragma unroll
      for (int e = 0; e < NEXP; ++e) lg[e] = acc[e] + bg[e];
      int i1 = 0; float v1 = lg[0];
#pragma unroll
      for (int e = 1; e < NEXP; ++e) if (lg[e] > v1) { v1 = lg[e]; i1 = e; }
      int i2 = -1; float v2 = -3.4e38f;
#pragma unroll
      for (int e = 0; e < NEXP; ++e) if (e != i1 && lg[e] > v2) { v2 = lg[e]; i2 = e; }
      float ez = __expf(v2 - v1);           // v2 <= v1
      float s = 1.f / (1.f + ez);
      sel[t*2] = i1; sel[t*2+1] = i2;
      wts[t*2] = s;  wts[t*2+1] = ez * s;   // no atomics: counts from sel in scan
    }
  } else if (b < GATE_BLKS + CVT_BLKS) {
    int i = (b - GATE_BLKS) * 256 + threadIdx.x;
    const float4* in4 = (const float4*)inputs;
    float4 v0 = in4[(size_t)i*2], v1 = in4[(size_t)i*2 + 1];
    union { unsigned short u[8]; uint4 q; } r;
    r.u[0]=f2bf(v0.x); r.u[1]=f2bf(v0.y); r.u[2]=f2bf(v0.z); r.u[3]=f2bf(v0.w);
    r.u[4]=f2bf(v1.x); r.u[5]=f2bf(v1.y); r.u[6]=f2bf(v1.z); r.u[7]=f2bf(v1.w);
    ((uint4*)Xb)[i] = r.q;
  } else {
    int bp = b - (GATE_BLKS + CVT_BLKS);   // 0..2047
    if (bp < 1024) {
      // w1 [E][K=1024][N=4096]: 128 groups/expert = kt(16) x nggrp(8)
      int e = bp >> 7, rem = bp & 127;
      tile_tr_pipe(w1, W1T, DMODEL, FDIM, e, rem >> 3, (rem & 7) * 8, tr_lds);
    } else {
      // w2 [E][K=4096][N=1024]: 128 groups/expert = kt(64) x nggrp(2)
      bp -= 1024;
      int e = bp >> 7, rem = bp & 127;
      tile_tr_pipe(w2, W2T, FDIM, DMODEL, e, rem >> 1, (rem & 1) * 8, tr_lds);
    }
  }
}

// ---------------- hist(sel) + offsets + 256-row tile table (1 block) ----------
__global__ __launch_bounds__(256) void scan_build_kernel(
    const int* __restrict__ sel, int* __restrict__ offsets,
    int* __restrict__ ntiles, int* __restrict__ t_e, int* __restrict__ t_r,
    int* __restrict__ t_rend)
{
  __shared__ int sc[8], soff[9], stile[9];
  int tid = threadIdx.x;
  if (tid < 8) sc[tid] = 0;
  __syncthreads();
  int cnt[NEXP];
#pragma unroll
  for (int e = 0; e < NEXP; ++e) cnt[e] = 0;
  for (int i = tid; i < NROWS; i += 256) {
    int v = sel[i];
#pragma unroll
    for (int e = 0; e < NEXP; ++e) cnt[e] += (v == e) ? 1 : 0;
  }
#pragma unroll
  for (int e = 0; e < NEXP; ++e) if (cnt[e]) atomicAdd(&sc[e], cnt[e]);
  __syncthreads();
  if (tid == 0) {
    int off = 0, tl = 0;
#pragma unroll
    for (int e = 0; e < NEXP; ++e) {
      soff[e] = off; stile[e] = tl;
      off += sc[e];
      tl += (sc[e] + 255) >> 8;
    }
    soff[8] = off; stile[8] = tl;
  }
  __syncthreads();
  int ntot = stile[8];
  for (int idx = tid; idx < ntot; idx += 256) {
    int e = 0;
#pragma unroll
    for (int q = 0; q < NEXP; ++q) if (idx >= stile[q + 1]) e = q + 1;
    int r = (idx - stile[e]) * 256;
    t_e[idx] = e; t_r[idx] = soff[e] + r; t_rend[idx] = soff[e] + sc[e];
  }
  if (tid < 9) offsets[tid] = soff[tid];
  if (tid == 0) *ntiles = ntot;
}

// ---------------- scatter: wave-aggregated per-expert atomics -----------------
__global__ __launch_bounds__(256) void scatter_kernel(
    const int* __restrict__ sel, int* __restrict__ cursors,
    const int* __restrict__ offsets, int* __restrict__ token_list,
    int* __restrict__ slot_list)
{
  int t = blockIdx.x * 256 + threadIdx.x;
  int lane = threadIdx.x & 63;
  unsigned long long ltmask = (lane == 63) ? 0x7fffffffffffffffull
                                           : ((1ull << lane) - 1ull);
#pragma unroll
  for (int k = 0; k < 2; ++k) {
    int e = sel[t*2 + k];
#pragma unroll
    for (int ex = 0; ex < NEXP; ++ex) {
      unsigned long long m = __ballot(e == ex);
      if (m == 0ull) continue;
      if (e == ex) {
        int leader = __ffsll((unsigned long long)m) - 1;
        int cnt = __popcll(m);
        int base = 0;
        if (lane == leader) base = atomicAdd(&cursors[ex], cnt);
        base = __shfl(base, leader);
        int r = offsets[ex] + base + __popcll(m & ltmask);
        token_list[r] = t;
        slot_list[r] = t*2 + k;
      }
    }
  }
}

// ---------------- grouped GEMM 256x256, BK=64, overlap-phase schedule ---------
// m201-faithful revision: ONE barrier/phase; quad p+1's ds_reads issued at END
// of phase p (overlap other waves' MFMA); every confirm is 2 PHASES after issue
// with a barrier in between (cross-wave safe, zero-stall).
// Stage plan (tile kt stages kt+1): P0:{A0,B0} P1:{B1} P2:{A1} P3:none.
// Waits: P0 vmcnt(4) [confirms A1(kt)]; P2 vmcnt(4) [A0,B0(kt+1)];
//        P3 vmcnt(2) [B1(kt+1)]. Gray-code regs: bR0 lives all tile; aR A0->A1.
template<bool G1>
__global__ __launch_bounds__(512, 2) void gemm256_kernel(
    const unsigned short* __restrict__ A, const unsigned short* __restrict__ B,
    const float* __restrict__ b1, const int* __restrict__ token_list,
    const int* __restrict__ slot_list,
    const int* __restrict__ tile_e, const int* __restrict__ tile_r,
    const int* __restrict__ tile_rend, const int* __restrict__ ntiles,
    unsigned short* __restrict__ outp)
{
  constexpr int KDIM = G1 ? DMODEL : FDIM;   // K extent
  constexpr int NKT  = KDIM / 64;
  constexpr int NOUT = G1 ? FDIM : DMODEL;   // output row width
  constexpr int KTB  = NOUT * 64;            // B k-tile stride (elements)

  int bid = blockIdx.x;
  int nb, bt;
  if constexpr (G1) {                        // 16 nb-panels: pin 2 per XCD, bt-major
    int xcd = bid & 7, idx = bid >> 3;
    nb = xcd * 2 + (idx & 1);
    bt = idx >> 1;
  } else {                                   // 4 nb-panels, bt-major
    nb = bid & 3;
    bt = bid >> 2;
  }
  if (bt >= *ntiles) return;
  const int e = tile_e[bt], row0 = tile_r[bt], rend = tile_rend[bt];
  const int n0 = nb * 256;

  const int tid = threadIdx.x, lane = tid & 63, wave = tid >> 6;
  extern __shared__ __align__(16) char smem[];   // 131072 B

  const int lr8 = lane >> 3, g8 = lane & 7, ch = g8 ^ lr8;

  int mA[2], mB[2];
#pragma unroll
  for (int p = 0; p < 2; ++p)
    mA[p] = (wave < 4) ? (p*64 + wave*16) : (128 + p*64 + (wave-4)*16);
#pragma unroll
  for (int nh = 0; nh < 2; ++nh)
    mB[nh] = (wave >> 1)*64 + nh*32 + (wave & 1)*16;

  const unsigned short* eB = B + (size_t)e * KDIM * NOUT;
  unsigned aoffs[2][2], boffs[2][2];
#pragma unroll
  for (int p = 0; p < 2; ++p)
#pragma unroll
    for (int l = 0; l < 2; ++l) {
      int m = mA[p] + l*8 + lr8;
      int row = row0 + m; if (row > NROWS - 1) row = NROWS - 1;
      int arow = G1 ? token_list[row] : row;
      aoffs[p][l] = (unsigned)arow * KDIM + ch*8;
      int mb = mB[p] + l*8 + lr8;
      boffs[p][l] = (unsigned)((n0 + mb) * 64 + ch*8);
    }

  auto stage_half = [&](int p, int ktn, int bsel) {
    char* base = smem + bsel * 65536;
    if (p < 2) {
      const int kb = ktn * 64;
#pragma unroll
      for (int l = 0; l < 2; ++l)
        __builtin_amdgcn_global_load_lds(
            (const AS1 void*)(A + aoffs[p][l] + kb),
            (AS3 void*)(base + ((mA[p] + l*8) << 7)), 16, 0, 0);
    } else {
      const int nh = p - 2;
      const unsigned short* bk = eB + (size_t)ktn * KTB;
#pragma unroll
      for (int l = 0; l < 2; ++l)
        __builtin_amdgcn_global_load_lds(
            (const AS1 void*)(bk + boffs[nh][l]),
            (AS3 void*)(base + 32768 + ((mB[nh] + l*8) << 7)), 16, 0, 0);
    }
  };

  f32x4 acc[8][4] = {};
  bf16x8 aR[4][2];        // current A-half: 4 row-frags x 2 k-slices
  bf16x8 bR[2][2][2];     // both B-halves: [nh][jj][ks]
  const int wr = wave >> 2, wc = wave & 3;
  const int lm = lane & 15, lk = lane >> 4, l7 = lane & 7;
  const unsigned abase = (unsigned)(wr*128 + lm) * 128;
  const unsigned bbase = 32768u + (unsigned)(wc*64 + lm) * 128;
  const unsigned kx0 = (unsigned)((lk ^ l7) << 4);
  const unsigned kx1 = (unsigned)(((4 + lk) ^ l7) << 4);

  auto rdA = [&](const char* base, int mh) {
#pragma unroll
    for (int i = 0; i < 4; ++i) {
      const char* pA = base + abase + mh*8192 + i*2048;
      aR[i][0] = *(const bf16x8*)(pA + kx0);
      aR[i][1] = *(const bf16x8*)(pA + kx1);
    }
  };
  auto rdB = [&](const char* base, int nh) {
#pragma unroll
    for (int jj = 0; jj < 2; ++jj) {
      const char* pB = base + bbase + nh*4096 + jj*2048;
      bR[nh][jj][0] = *(const bf16x8*)(pB + kx0);
      bR[nh][jj][1] = *(const bf16x8*)(pB + kx1);
    }
  };
  auto mm = [&](int mh, int nh) {
    __builtin_amdgcn_s_setprio(1);
#pragma unroll
    for (int i = 0; i < 4; ++i)
#pragma unroll
      for (int jj = 0; jj < 2; ++jj) {
        acc[mh*4+i][nh*2+jj] = __builtin_amdgcn_mfma_f32_16x16x32_bf16(
            aR[i][0], bR[nh][jj][0], acc[mh*4+i][nh*2+jj], 0, 0, 0);
        acc[mh*4+i][nh*2+jj] = __builtin_amdgcn_mfma_f32_16x16x32_bf16(
            aR[i][1], bR[nh][jj][1], acc[mh*4+i][nh*2+jj], 0, 0, 0);
      }
    __builtin_amdgcn_s_setprio(0);
  };

  // prologue: stage tile0 A0,B0,B1,A1; confirm A0,B0,B1; barrier; rd quad0
  stage_half(0, 0, 0);   // A0
  stage_half(2, 0, 0);   // B0
  stage_half(3, 0, 0);   // B1
  stage_half(1, 0, 0);   // A1
  asm volatile("s_waitcnt vmcnt(2)" ::: "memory");
  __builtin_amdgcn_s_barrier();
  __builtin_amdgcn_sched_barrier(0);
  rdA((const char*)smem, 0); rdB((const char*)smem, 0);
  __builtin_amdgcn_sched_barrier(0);

  for (int kt = 0; kt < NKT; ++kt) {
    const int b = kt & 1, nxt = b ^ 1;
    const char* base = smem + b * 65536;
    const char* nbase = smem + nxt * 65536;
    const bool pre = (kt + 1 < NKT);
    // ---- P0: mm(0,0); stage A0,B0(kt+1); confirm A1(kt); rd B1(kt) ----
    __builtin_amdgcn_s_barrier();
    asm volatile("s_waitcnt lgkmcnt(0)" ::: "memory");
    __builtin_amdgcn_sched_barrier(0);
    mm(0, 0);
    if (pre) {
      stage_half(0, kt + 1, nxt);
      stage_half(2, kt + 1, nxt);
      asm volatile("s_waitcnt vmcnt(4)" ::: "memory");
    } else {
      asm volatile("s_waitcnt vmcnt(0)" ::: "memory");
    }
    rdB(base, 1);
    __builtin_amdgcn_sched_barrier(0);
    // ---- P1: mm(0,1); stage B1(kt+1); rd A1(kt) ----
    __builtin_amdgcn_s_barrier();
    asm volatile("s_waitcnt lgkmcnt(0)" ::: "memory");
    __builtin_amdgcn_sched_barrier(0);
    mm(0, 1);
    if (pre) stage_half(3, kt + 1, nxt);
    rdA(base, 1);
    __builtin_amdgcn_sched_barrier(0);
    // ---- P2: mm(1,1); stage A1(kt+1); confirm A0,B0(kt+1) ----
    __builtin_amdgcn_s_barrier();
    asm volatile("s_waitcnt lgkmcnt(0)" ::: "memory");
    __builtin_amdgcn_sched_barrier(0);
    mm(1, 1);
    if (pre) {
      stage_half(1, kt + 1, nxt);
      asm volatile("s_waitcnt vmcnt(4)" ::: "memory");
    }
    __builtin_amdgcn_sched_barrier(0);
    // ---- P3: mm(1,0); confirm B1(kt+1); rd A0,B0(kt+1) ----
    __builtin_amdgcn_s_barrier();
    __builtin_amdgcn_sched_barrier(0);
    mm(1, 0);
    if (pre) {
      asm volatile("s_waitcnt vmcnt(2)" ::: "memory");
      rdA(nbase, 0); rdB(nbase, 0);
    }
    __builtin_amdgcn_sched_barrier(0);
  }

  asm volatile("" ::: "memory");
  float bias[4] = {};
  if constexpr (G1) {
#pragma unroll
    for (int j = 0; j < 4; ++j) bias[j] = b1[(size_t)e * FDIM + n0 + wc*64 + j*16 + lm];
  }

  // epilogue: 8 chunks of 32 rows; [gelu] -> f32 LDS (stride 260) -> bf16 x8
  float* eps = (float*)smem;
#pragma unroll
  for (int c = 0; c < 8; ++c) {
    __syncthreads();
    if (wr == (c >> 2)) {
#pragma unroll
      for (int ii = 0; ii < 2; ++ii) {
        const int mi = (c & 3) * 2 + ii;
#pragma unroll
        for (int j = 0; j < 4; ++j) {
#pragma unroll
          for (int r = 0; r < 4; ++r) {
            float v = acc[mi][j][r];
            if constexpr (G1) {
              v += bias[j];
              float z2 = 1.5957691216f * (v + 0.044715f * v * v * v);
              v = v / (1.f + __expf(-z2));
            }
            eps[(ii*16 + lk*4 + r) * 260 + wc*64 + j*16 + lm] = v;
          }
        }
      }
    }
    __syncthreads();
#pragma unroll
    for (int u = 0; u < 2; ++u) {
      int item = u * 512 + tid;               // 1024 items: 32 rows x 32 octs
      int lrow = item >> 5, c8 = (item & 31) * 8;
      int gr = row0 + c * 32 + lrow;
      if (gr < rend) {
        float4 v0 = *(const float4*)&eps[lrow * 260 + c8];
        float4 v1 = *(const float4*)&eps[lrow * 260 + c8 + 4];
        union { unsigned short u[8]; uint4 q; } pk;
        pk.u[0]=f2bf(v0.x); pk.u[1]=f2bf(v0.y); pk.u[2]=f2bf(v0.z); pk.u[3]=f2bf(v0.w);
        pk.u[4]=f2bf(v1.x); pk.u[5]=f2bf(v1.y); pk.u[6]=f2bf(v1.z); pk.u[7]=f2bf(v1.w);
        size_t orow;
        if constexpr (G1) orow = (size_t)gr * FDIM;
        else              orow = (size_t)slot_list[gr] * DMODEL;
        *(uint4*)(outp + orow + n0 + c8) = pk.q;
      }
    }
  }
}

// ---------------- combine: out = sum_k w_k*(y_k + b2[e_k]) --------------------
__global__ __launch_bounds__(256) void combine_kernel(
    const unsigned short* __restrict__ ys, const float* __restrict__ wts,
    const int* __restrict__ sel, const float* __restrict__ b2,
    float* __restrict__ out)
{
  int i = blockIdx.x * 256 + threadIdx.x;   // over T*D/8
  int t = i >> 7, d8 = i & 127;
  float w0 = wts[t*2], w1 = wts[t*2 + 1];
  int e0 = sel[t*2], e1 = sel[t*2 + 1];
  const uint4* ys4 = (const uint4*)ys;
  uint4 ya = ys4[(size_t)(t*2) * 128 + d8];
  uint4 yb = ys4[(size_t)(t*2 + 1) * 128 + d8];
  const float4* b24 = (const float4*)b2;
  float4 c0a = b24[e0*256 + d8*2], c0b = b24[e0*256 + d8*2 + 1];
  float4 c1a = b24[e1*256 + d8*2], c1b = b24[e1*256 + d8*2 + 1];
  float4 o0, o1;
  o0.x = w0*(bflo(ya.x)+c0a.x) + w1*(bflo(yb.x)+c1a.x);
  o0.y = w0*(bfhi(ya.x)+c0a.y) + w1*(bfhi(yb.x)+c1a.y);
  o0.z = w0*(bflo(ya.y)+c0a.z) + w1*(bflo(yb.y)+c1a.z);
  o0.w = w0*(bfhi(ya.y)+c0a.w) + w1*(bfhi(yb.y)+c1a.w);
  o1.x = w0*(bflo(ya.z)+c0b.x) + w1*(bflo(yb.z)+c1b.x);
  o1.y = w0*(bfhi(ya.z)+c0b.y) + w1*(bfhi(yb.z)+c1b.y);
  o1.z = w0*(bflo(ya.w)+c0b.z) + w1*(bflo(yb.w)+c1b.z);
  o1.w = w0*(bfhi(ya.w)+c0b.w) + w1*(bfhi(yb.w)+c1b.w);
  float4* out4 = (float4*)out;
  out4[(size_t)t * 256 + d8*2]     = o0;
  out4[(size_t)t * 256 + d8*2 + 1] = o1;
}

// ---------------- host ---------------------------------------------------------
extern "C" void kernel_launch(void* const* d_in, const int* in_sizes, int n_in,
                              void* d_out, int out_size, void* d_ws, size_t ws_size,
                              hipStream_t stream)
{
  const float* gate_inputs = (const float*)d_in[0];
  const float* inputs      = (const float*)d_in[1];
  const float* Wg          = (const float*)d_in[2];
  const float* bg          = (const float*)d_in[3];
  const float* w1          = (const float*)d_in[4];
  const float* b1          = (const float*)d_in[5];
  const float* w2          = (const float*)d_in[6];
  const float* b2          = (const float*)d_in[7];
  float* out = (float*)d_out;

  char* ws = (char*)d_ws;
  size_t o = 0;
  auto carve = [&](size_t bytes) { void* p = ws + o; o += (bytes + 255) & ~(size_t)255; return p; };
  unsigned short* Xb  = (unsigned short*)carve((size_t)T_TOK * DMODEL * 2);
  unsigned short* W1T = (unsigned short*)carve((size_t)NEXP * FDIM * DMODEL * 2);
  unsigned short* W2T = (unsigned short*)carve((size_t)NEXP * DMODEL * FDIM * 2);
  unsigned short* H   = (unsigned short*)carve((size_t)NROWS * FDIM * 2);
  unsigned short* ys  = (unsigned short*)carve((size_t)NROWS * DMODEL * 2);
  int*   sel          = (int*)carve((size_t)NROWS * 4);
  float* wts          = (float*)carve((size_t)NROWS * 4);
  int*   token_list   = (int*)carve((size_t)(NROWS + 256) * 4);
  int*   slot_list    = (int*)carve((size_t)(NROWS + 256) * 4);
  int*   ctrl         = (int*)carve(4096);
  int* cursors = ctrl + 8;        // 8
  int* offsets = ctrl + 16;       // 9
  int* ntiles  = ctrl + 28;       // 1
  int* t_e     = ctrl + 32;
  int* t_r     = ctrl + 32 + MAXT;
  int* t_rend  = ctrl + 32 + 2 * MAXT;

  hipMemsetAsync(ctrl, 0, 64, stream);  // cursors

  prep_kernel<<<PREP_BLKS, 256, 0, stream>>>(
      gate_inputs, Wg, bg, sel, wts,
      inputs, Xb, w1, W1T, w2, W2T);
  scan_build_kernel<<<1, 256, 0, stream>>>(sel, offsets, ntiles, t_e, t_r, t_rend);
  scatter_kernel<<<T_TOK / 256, 256, 0, stream>>>(sel, cursors, offsets, token_list, slot_list);

  hipFuncSetAttribute((const void*)gemm256_kernel<true>,
                      hipFuncAttributeMaxDynamicSharedMemorySize, 131072);
  hipFuncSetAttribute((const void*)gemm256_kernel<false>,
                      hipFuncAttributeMaxDynamicSharedMemorySize, 131072);
  // gemm1: H = gelu(X@W1+b1). grid = 8 xcd * (2 nb-sub * 80 bt)
  gemm256_kernel<true><<<8 * 2 * MAXT, 512, 131072, stream>>>(
      Xb, W1T, b1, token_list, nullptr, t_e, t_r, t_rend, ntiles, H);
  // gemm2: ys = H@W2 scatter. grid = 4 nb * 80 bt
  gemm256_kernel<false><<<4 * MAXT, 512, 131072, stream>>>(
      H, W2T, nullptr, nullptr, slot_list, t_e, t_r, t_rend, ntiles, ys);
  combine_kernel<<<(T_TOK * DMODEL / 8) / 256, 256, 0, stream>>>(ys, wts, sel, b2, out);
}